// Round 1
// baseline (300.949 us; speedup 1.0000x reference)
//
#include <hip/hip_runtime.h>

#define DEV __device__ __forceinline__

typedef __attribute__((ext_vector_type(4))) float f32x4;
typedef __attribute__((ext_vector_type(8))) short bf16x8;

// round-to-nearest-even f32 -> bf16 (bits in a short)
DEV short f2bf(float f) {
    union { float f; unsigned u; } v; v.f = f;
    unsigned r = (v.u + 0x7fffu + ((v.u >> 16) & 1u)) >> 16;
    return (short)r;
}

// async global->LDS, 16 bytes per lane. LDS dest = wave-uniform base + lane*16.
DEV void gl_lds16(const void* g, void* l) {
    __builtin_amdgcn_global_load_lds(
        (__attribute__((address_space(1))) void*)(g),
        (__attribute__((address_space(3))) void*)(l), 16, 0, 0);
}

// Stage ITERS*32 rows x 64 bf16 cols from row-major global (stride ldg shorts)
// into LDS tile with row stride 64 shorts. 16B chunks XOR-swizzled:
// slot s of row r holds chunk s ^ (r&7)  -> conflict-free ds_read_b128 later.
template <int ITERS>
DEV void stage_tile(const short* g, int ldg, short* lds, int t) {
    const int w = t >> 6;
#pragma unroll
    for (int it = 0; it < ITERS; ++it) {
        int row = it * 32 + (t >> 3);
        int cx = (t & 7) ^ ((t >> 3) & 7);
        gl_lds16(g + row * ldg + cx * 8, (char*)lds + it * 4096 + (w << 10));
    }
}

// read 8-bf16 fragment: chunk kc (0..7) of tile row r (row stride 64 shorts)
DEV bf16x8 ldfrag(const short* lds, int r, int kc) {
    return *(const bf16x8*)(lds + r * 64 + ((kc ^ (r & 7)) << 3));
}

// ---------------- conversion ----------------
__global__ void cvt_bf16(const float* __restrict__ s, short* __restrict__ d, int n4) {
    int i = blockIdx.x * 256 + threadIdx.x;
    if (i >= n4) return;
    float4 v = ((const float4*)s)[i];
    short4 o;
    o.x = f2bf(v.x); o.y = f2bf(v.y); o.z = f2bf(v.z); o.w = f2bf(v.w);
    ((short4*)d)[i] = o;
}

// ---------------- QKV projection GEMM ----------------
// C = xb @ W^T  (x:[8192,768] bf16, W:[768,768] bf16 row-major)
// z=0: Q (scale 1/8 folded) -> [96,1024,64]; z=1: K -> [96,1024,64]; z=2: V^T -> [96,64,1024]
__global__ __launch_bounds__(256) void proj_gemm(
    const short* __restrict__ xb,
    const short* __restrict__ wq, const short* __restrict__ wk, const short* __restrict__ wv,
    short* __restrict__ Qg, short* __restrict__ Kg, short* __restrict__ Vtg)
{
    __shared__ __align__(16) short At[128 * 64];
    __shared__ __align__(16) short Bt[128 * 64];
    const int t = threadIdx.x;
    const int z = blockIdx.z;
    const int row0 = blockIdx.x * 128, col0 = blockIdx.y * 128;
    const int lane = t & 63, w = t >> 6, quad = lane >> 4, c = lane & 15;
    const int wm = w >> 1, wn = w & 1;
    const short* W = (z == 0) ? wq : (z == 1) ? wk : wv;

    f32x4 acc[4][4];
#pragma unroll
    for (int i = 0; i < 4; ++i)
#pragma unroll
        for (int j = 0; j < 4; ++j) acc[i][j] = (f32x4){0.f, 0.f, 0.f, 0.f};

    for (int k0 = 0; k0 < 768; k0 += 64) {
        __syncthreads();
        stage_tile<4>(xb + (size_t)row0 * 768 + k0, 768, At, t);
        stage_tile<4>(W + (size_t)col0 * 768 + k0, 768, Bt, t);
        __syncthreads();
#pragma unroll
        for (int ks = 0; ks < 2; ++ks) {
            bf16x8 af[4], bfr[4];
#pragma unroll
            for (int fm = 0; fm < 4; ++fm) af[fm] = ldfrag(At, wm * 64 + fm * 16 + c, ks * 4 + quad);
#pragma unroll
            for (int fn = 0; fn < 4; ++fn) bfr[fn] = ldfrag(Bt, wn * 64 + fn * 16 + c, ks * 4 + quad);
#pragma unroll
            for (int fm = 0; fm < 4; ++fm)
#pragma unroll
                for (int fn = 0; fn < 4; ++fn)
                    acc[fm][fn] = __builtin_amdgcn_mfma_f32_16x16x32_bf16(af[fm], bfr[fn], acc[fm][fn], 0, 0, 0);
        }
    }

#pragma unroll
    for (int fm = 0; fm < 4; ++fm) {
#pragma unroll
        for (int fn = 0; fn < 4; ++fn) {
            int gr0 = row0 + wm * 64 + fm * 16 + quad * 4;
            int gc = col0 + wn * 64 + fn * 16 + c;
            int hh = gc >> 6, dd = gc & 63;
#pragma unroll
            for (int reg = 0; reg < 4; ++reg) {
                int gr = gr0 + reg;
                int bb = gr >> 10, rr = gr & 1023;
                int head = bb * 12 + hh;
                float val = acc[fm][fn][reg];
                if (z == 0)      Qg[((size_t)head * 1024 + rr) * 64 + dd] = f2bf(val * 0.125f);
                else if (z == 1) Kg[((size_t)head * 1024 + rr) * 64 + dd] = f2bf(val);
                else             Vtg[((size_t)head * 64 + dd) * 1024 + rr] = f2bf(val);
            }
        }
    }
}

// ---------------- LSE pass (no-max online logsumexp; args are bounded) ----------------
// out[row] = out_sign * log( sum_col exp( A_row . B_col + bias_sign*bias[col] ) )
// A,B: per-head [1024,64] bf16. bias may be null.
__global__ __launch_bounds__(256) void lse_pass(
    const short* __restrict__ Aall, const short* __restrict__ Ball,
    const float* __restrict__ bias, float* __restrict__ outv,
    float bias_sign, float out_sign)
{
    __shared__ __align__(16) short At[128 * 64];
    __shared__ __align__(16) short Bt[128 * 64];
    __shared__ __align__(16) float biasl[1024];
    const int t = threadIdx.x;
    const int head = blockIdx.y;
    const int r0 = blockIdx.x * 128;
    const int lane = t & 63, w = t >> 6, quad = lane >> 4, c = lane & 15;
    const short* A = Aall + (size_t)head * 65536;
    const short* B = Ball + (size_t)head * 65536;

    stage_tile<4>(A + r0 * 64, 64, At, t);
    if (bias) ((float4*)biasl)[t] = ((const float4*)(bias + (size_t)head * 1024))[t];
    else      ((float4*)biasl)[t] = make_float4(0.f, 0.f, 0.f, 0.f);

    float lsum[2][4];
#pragma unroll
    for (int fm = 0; fm < 2; ++fm)
#pragma unroll
        for (int reg = 0; reg < 4; ++reg) lsum[fm][reg] = 0.f;

    for (int j0 = 0; j0 < 1024; j0 += 128) {
        __syncthreads();
        stage_tile<4>(B + j0 * 64, 64, Bt, t);
        __syncthreads();
        f32x4 sacc[2][8];
#pragma unroll
        for (int fm = 0; fm < 2; ++fm)
#pragma unroll
            for (int fn = 0; fn < 8; ++fn) sacc[fm][fn] = (f32x4){0.f, 0.f, 0.f, 0.f};
#pragma unroll
        for (int ks = 0; ks < 2; ++ks) {
            bf16x8 af[2], bfr[8];
#pragma unroll
            for (int fm = 0; fm < 2; ++fm) af[fm] = ldfrag(At, w * 32 + fm * 16 + c, ks * 4 + quad);
#pragma unroll
            for (int fn = 0; fn < 8; ++fn) bfr[fn] = ldfrag(Bt, fn * 16 + c, ks * 4 + quad);
#pragma unroll
            for (int fm = 0; fm < 2; ++fm)
#pragma unroll
                for (int fn = 0; fn < 8; ++fn)
                    sacc[fm][fn] = __builtin_amdgcn_mfma_f32_16x16x32_bf16(af[fm], bfr[fn], sacc[fm][fn], 0, 0, 0);
        }
#pragma unroll
        for (int fn = 0; fn < 8; ++fn) {
            float bv = biasl[j0 + fn * 16 + c] * bias_sign;
#pragma unroll
            for (int fm = 0; fm < 2; ++fm)
#pragma unroll
                for (int reg = 0; reg < 4; ++reg)
                    lsum[fm][reg] += __expf(sacc[fm][fn][reg] + bv);
        }
    }

#pragma unroll
    for (int fm = 0; fm < 2; ++fm)
#pragma unroll
        for (int reg = 0; reg < 4; ++reg) {
            float s = lsum[fm][reg];
            s += __shfl_xor(s, 1); s += __shfl_xor(s, 2);
            s += __shfl_xor(s, 4); s += __shfl_xor(s, 8);
            lsum[fm][reg] = s;
        }
    if (c == 0) {
#pragma unroll
        for (int fm = 0; fm < 2; ++fm)
#pragma unroll
            for (int reg = 0; reg < 4; ++reg)
                outv[(size_t)head * 1024 + r0 + w * 32 + fm * 16 + quad * 4 + reg] =
                    out_sign * __logf(lsum[fm][reg]);
    }
}

// ---------------- flash pass: ctx = (1/n) softmax_j(S+v1) @ V ----------------
__global__ __launch_bounds__(256) void flash_pass(
    const short* __restrict__ Qall, const short* __restrict__ Kall,
    const short* __restrict__ Vtall, const float* __restrict__ v1,
    short* __restrict__ ctx)
{
    __shared__ __align__(16) short Qt[128 * 64];
    __shared__ __align__(16) short Kt[64 * 64];
    __shared__ __align__(16) short Vtl[64 * 64];
    __shared__ __align__(16) short Pl[4][32 * 72];   // padded stride 72 shorts (144B)
    __shared__ __align__(16) float v1l[1024];
    const int t = threadIdx.x;
    const int head = blockIdx.y;
    const int r0 = blockIdx.x * 128;
    const int lane = t & 63, w = t >> 6, quad = lane >> 4, c = lane & 15;
    const short* Q = Qall + (size_t)head * 65536;
    const short* K = Kall + (size_t)head * 65536;
    const short* Vt = Vtall + (size_t)head * 65536;

    stage_tile<4>(Q + r0 * 64, 64, Qt, t);
    ((float4*)v1l)[t] = ((const float4*)(v1 + (size_t)head * 1024))[t];

    float lsum[2][4];
    f32x4 oacc[2][4];
#pragma unroll
    for (int fm = 0; fm < 2; ++fm)
#pragma unroll
        for (int x = 0; x < 4; ++x) { lsum[fm][x] = 0.f; oacc[fm][x] = (f32x4){0.f, 0.f, 0.f, 0.f}; }
    short* myP = Pl[w];

    for (int j0 = 0; j0 < 1024; j0 += 64) {
        __syncthreads();
        stage_tile<2>(K + j0 * 64, 64, Kt, t);
        stage_tile<2>(Vt + j0, 1024, Vtl, t);
        __syncthreads();
        // S strip: rows w*32..w*32+32, cols j0..j0+64
        f32x4 sacc[2][4];
#pragma unroll
        for (int fm = 0; fm < 2; ++fm)
#pragma unroll
            for (int fn = 0; fn < 4; ++fn) sacc[fm][fn] = (f32x4){0.f, 0.f, 0.f, 0.f};
#pragma unroll
        for (int ks = 0; ks < 2; ++ks) {
            bf16x8 af[2], bfr[4];
#pragma unroll
            for (int fm = 0; fm < 2; ++fm) af[fm] = ldfrag(Qt, w * 32 + fm * 16 + c, ks * 4 + quad);
#pragma unroll
            for (int fn = 0; fn < 4; ++fn) bfr[fn] = ldfrag(Kt, fn * 16 + c, ks * 4 + quad);
#pragma unroll
            for (int fm = 0; fm < 2; ++fm)
#pragma unroll
                for (int fn = 0; fn < 4; ++fn)
                    sacc[fm][fn] = __builtin_amdgcn_mfma_f32_16x16x32_bf16(af[fm], bfr[fn], sacc[fm][fn], 0, 0, 0);
        }
        // P = exp(S + v1), accumulate row sums, round-trip P through LDS (C->A layout)
#pragma unroll
        for (int fn = 0; fn < 4; ++fn) {
            float bv = v1l[j0 + fn * 16 + c];
#pragma unroll
            for (int fm = 0; fm < 2; ++fm)
#pragma unroll
                for (int reg = 0; reg < 4; ++reg) {
                    float p = __expf(sacc[fm][fn][reg] + bv);
                    lsum[fm][reg] += p;
                    myP[(fm * 16 + quad * 4 + reg) * 72 + fn * 16 + c] = f2bf(p);
                }
        }
        asm volatile("s_waitcnt lgkmcnt(0)" ::: "memory");
        // O += P @ V   (B-frag from Vt tile rows = dd)
#pragma unroll
        for (int ks2 = 0; ks2 < 2; ++ks2) {
            bf16x8 paf[2], vbf[4];
#pragma unroll
            for (int fm = 0; fm < 2; ++fm)
                paf[fm] = *(const bf16x8*)(myP + (fm * 16 + c) * 72 + ks2 * 32 + quad * 8);
#pragma unroll
            for (int fn = 0; fn < 4; ++fn) vbf[fn] = ldfrag(Vtl, fn * 16 + c, ks2 * 4 + quad);
#pragma unroll
            for (int fm = 0; fm < 2; ++fm)
#pragma unroll
                for (int fn = 0; fn < 4; ++fn)
                    oacc[fm][fn] = __builtin_amdgcn_mfma_f32_16x16x32_bf16(paf[fm], vbf[fn], oacc[fm][fn], 0, 0, 0);
        }
    }

#pragma unroll
    for (int fm = 0; fm < 2; ++fm)
#pragma unroll
        for (int reg = 0; reg < 4; ++reg) {
            float s = lsum[fm][reg];
            s += __shfl_xor(s, 1); s += __shfl_xor(s, 2);
            s += __shfl_xor(s, 4); s += __shfl_xor(s, 8);
            lsum[fm][reg] = 1.f / (1024.f * s);
        }
    const int bb = head / 12, hh = head % 12;
#pragma unroll
    for (int fm = 0; fm < 2; ++fm)
#pragma unroll
        for (int fn = 0; fn < 4; ++fn)
#pragma unroll
            for (int reg = 0; reg < 4; ++reg) {
                int rr = r0 + w * 32 + fm * 16 + quad * 4 + reg;
                ctx[((size_t)(bb * 1024 + rr)) * 768 + hh * 64 + fn * 16 + c] =
                    f2bf(oacc[fm][fn][reg] * lsum[fm][reg]);
            }
}

// ---------------- output projection ----------------
__global__ __launch_bounds__(256) void out_gemm(
    const short* __restrict__ ctxb, const short* __restrict__ wo,
    const float* __restrict__ bo, float* __restrict__ out)
{
    __shared__ __align__(16) short At[128 * 64];
    __shared__ __align__(16) short Bt[128 * 64];
    const int t = threadIdx.x;
    const int row0 = blockIdx.x * 128, col0 = blockIdx.y * 128;
    const int lane = t & 63, w = t >> 6, quad = lane >> 4, c = lane & 15;
    const int wm = w >> 1, wn = w & 1;

    f32x4 acc[4][4];
#pragma unroll
    for (int i = 0; i < 4; ++i)
#pragma unroll
        for (int j = 0; j < 4; ++j) acc[i][j] = (f32x4){0.f, 0.f, 0.f, 0.f};

    for (int k0 = 0; k0 < 768; k0 += 64) {
        __syncthreads();
        stage_tile<4>(ctxb + (size_t)row0 * 768 + k0, 768, At, t);
        stage_tile<4>(wo + (size_t)col0 * 768 + k0, 768, Bt, t);
        __syncthreads();
#pragma unroll
        for (int ks = 0; ks < 2; ++ks) {
            bf16x8 af[4], bfr[4];
#pragma unroll
            for (int fm = 0; fm < 4; ++fm) af[fm] = ldfrag(At, wm * 64 + fm * 16 + c, ks * 4 + quad);
#pragma unroll
            for (int fn = 0; fn < 4; ++fn) bfr[fn] = ldfrag(Bt, wn * 64 + fn * 16 + c, ks * 4 + quad);
#pragma unroll
            for (int fm = 0; fm < 4; ++fm)
#pragma unroll
                for (int fn = 0; fn < 4; ++fn)
                    acc[fm][fn] = __builtin_amdgcn_mfma_f32_16x16x32_bf16(af[fm], bfr[fn], acc[fm][fn], 0, 0, 0);
        }
    }
#pragma unroll
    for (int fm = 0; fm < 4; ++fm)
#pragma unroll
        for (int fn = 0; fn < 4; ++fn) {
            int gr0 = row0 + wm * 64 + fm * 16 + quad * 4;
            int gc = col0 + wn * 64 + fn * 16 + c;
            float b = bo[gc];
#pragma unroll
            for (int reg = 0; reg < 4; ++reg)
                out[(size_t)(gr0 + reg) * 768 + gc] = acc[fm][fn][reg] + b;
        }
}

extern "C" void kernel_launch(void* const* d_in, const int* in_sizes, int n_in,
                              void* d_out, int out_size, void* d_ws, size_t ws_size,
                              hipStream_t stream) {
    const float* x  = (const float*)d_in[0];
    const float* Wq = (const float*)d_in[1];
    const float* Wk = (const float*)d_in[2];
    const float* Wv = (const float*)d_in[3];
    const float* Wo = (const float*)d_in[4];
    const float* bo = (const float*)d_in[5];
    float* out = (float*)d_out;

    char* p = (char*)d_ws;
    short* xb  = (short*)p; p += (size_t)8192 * 768 * 2;
    short* wqb = (short*)p; p += (size_t)768 * 768 * 2;
    short* wkb = (short*)p; p += (size_t)768 * 768 * 2;
    short* wvb = (short*)p; p += (size_t)768 * 768 * 2;
    short* wob = (short*)p; p += (size_t)768 * 768 * 2;
    short* Qg  = (short*)p; p += (size_t)96 * 1024 * 64 * 2;
    short* Kg  = (short*)p; p += (size_t)96 * 1024 * 64 * 2;
    short* Vtg = (short*)p; p += (size_t)96 * 1024 * 64 * 2;
    float* r1  = (float*)p; p += (size_t)96 * 1024 * 4;
    float* v1  = (float*)p; p += (size_t)96 * 1024 * 4;
    short* ctx = (short*)p; p += (size_t)8192 * 768 * 2;

    cvt_bf16<<<6144, 256, 0, stream>>>(x, xb, 1572864);
    cvt_bf16<<<576, 256, 0, stream>>>(Wq, wqb, 147456);
    cvt_bf16<<<576, 256, 0, stream>>>(Wk, wkb, 147456);
    cvt_bf16<<<576, 256, 0, stream>>>(Wv, wvb, 147456);
    cvt_bf16<<<576, 256, 0, stream>>>(Wo, wob, 147456);

    proj_gemm<<<dim3(64, 6, 3), 256, 0, stream>>>(xb, wqb, wkb, wvb, Qg, Kg, Vtg);

    // pass 1: r1[i] = +log sum_j exp(S[i,j])
    lse_pass<<<dim3(8, 96), 256, 0, stream>>>(Qg, Kg, nullptr, r1, 0.f, 1.f);
    // pass 2: v1[j] = -log sum_i exp(S[i,j] - r1[i])   (A=K, B=Q, bias=-r1)
    lse_pass<<<dim3(8, 96), 256, 0, stream>>>(Kg, Qg, r1, v1, -1.f, -1.f);

    flash_pass<<<dim3(8, 96), 256, 0, stream>>>(Qg, Kg, Vtg, v1, ctx);

    out_gemm<<<dim3(64, 6), 256, 0, stream>>>(ctx, wob, bo, out);
}

// Round 2
// 278.716 us; speedup vs baseline: 1.0798x; 1.0798x over previous
//
#include <hip/hip_runtime.h>

#define DEV __device__ __forceinline__

typedef __attribute__((ext_vector_type(4))) float f32x4;
typedef __attribute__((ext_vector_type(8))) short bf16x8;

// round-to-nearest-even f32 -> bf16 (bits in a short)
DEV short f2bf(float f) {
    union { float f; unsigned u; } v; v.f = f;
    unsigned r = (v.u + 0x7fffu + ((v.u >> 16) & 1u)) >> 16;
    return (short)r;
}

// async global->LDS, 16 bytes per lane. LDS dest = wave-uniform base + lane*16.
DEV void gl_lds16(const void* g, void* l) {
    __builtin_amdgcn_global_load_lds(
        (__attribute__((address_space(1))) void*)(g),
        (__attribute__((address_space(3))) void*)(l), 16, 0, 0);
}

// Stage ITERS*32 rows x 64 bf16 cols from row-major global (stride ldg shorts)
// into LDS tile with row stride 64 shorts. 16B chunks XOR-swizzled:
// slot s of row r holds chunk s ^ (r&7)  -> conflict-free ds_read_b128 later.
template <int ITERS>
DEV void stage_tile(const short* g, int ldg, short* lds, int t) {
    const int w = t >> 6;
#pragma unroll
    for (int it = 0; it < ITERS; ++it) {
        int row = it * 32 + (t >> 3);
        int cx = (t & 7) ^ ((t >> 3) & 7);
        gl_lds16(g + row * ldg + cx * 8, (char*)lds + it * 4096 + (w << 10));
    }
}

// read 8-bf16 fragment: chunk kc (0..7) of tile row r (row stride 64 shorts)
DEV bf16x8 ldfrag(const short* lds, int r, int kc) {
    return *(const bf16x8*)(lds + r * 64 + ((kc ^ (r & 7)) << 3));
}

// ---------------- conversion (all 5 tensors in one launch) ----------------
__global__ void cvt_all(const float* __restrict__ x,
                        const float* __restrict__ wq, const float* __restrict__ wk,
                        const float* __restrict__ wv, const float* __restrict__ wo,
                        short* __restrict__ xb,
                        short* __restrict__ wqb, short* __restrict__ wkb,
                        short* __restrict__ wvb, short* __restrict__ wob) {
    int b = blockIdx.x;
    const float* s; short* d; int i;
    if (b < 6144) {
        s = x; d = xb; i = b * 256 + threadIdx.x;
    } else {
        int r = b - 6144;
        int wi = r / 576, rem = r - wi * 576;
        s = (wi == 0) ? wq : (wi == 1) ? wk : (wi == 2) ? wv : wo;
        d = (wi == 0) ? wqb : (wi == 1) ? wkb : (wi == 2) ? wvb : wob;
        i = rem * 256 + threadIdx.x;
    }
    float4 v = ((const float4*)s)[i];
    short4 o;
    o.x = f2bf(v.x); o.y = f2bf(v.y); o.z = f2bf(v.z); o.w = f2bf(v.w);
    ((short4*)d)[i] = o;
}

// ---------------- QKV projection GEMM ----------------
// C = xb @ W^T  (x:[8192,768] bf16, W:[768,768] bf16 row-major)
// z=0: Q (scale 1/8 folded) -> [96,1024,64]; z=1: K -> [96,1024,64]; z=2: V^T -> [96,64,1024]
// Epilogue routes through LDS (transposed for z=2) so global stores are short8-coalesced.
#define TSTRIDE 136
__global__ __launch_bounds__(256) void proj_gemm(
    const short* __restrict__ xb,
    const short* __restrict__ wq, const short* __restrict__ wk, const short* __restrict__ wv,
    short* __restrict__ Qg, short* __restrict__ Kg, short* __restrict__ Vtg)
{
    __shared__ __align__(16) char smem[128 * TSTRIDE * 2];  // 34816 B >= At+Bt (32768)
    short* At = (short*)smem;
    short* Bt = (short*)(smem + 128 * 64 * 2);
    short* Ct = (short*)smem;
    const int t = threadIdx.x;
    const int z = blockIdx.z;
    const int row0 = blockIdx.x * 128, col0 = blockIdx.y * 128;
    const int lane = t & 63, w = t >> 6, quad = lane >> 4, c = lane & 15;
    const int wm = w >> 1, wn = w & 1;
    const short* W = (z == 0) ? wq : (z == 1) ? wk : wv;

    f32x4 acc[4][4];
#pragma unroll
    for (int i = 0; i < 4; ++i)
#pragma unroll
        for (int j = 0; j < 4; ++j) acc[i][j] = (f32x4){0.f, 0.f, 0.f, 0.f};

    for (int k0 = 0; k0 < 768; k0 += 64) {
        __syncthreads();
        stage_tile<4>(xb + (size_t)row0 * 768 + k0, 768, At, t);
        stage_tile<4>(W + (size_t)col0 * 768 + k0, 768, Bt, t);
        __syncthreads();
#pragma unroll
        for (int ks = 0; ks < 2; ++ks) {
            bf16x8 af[4], bfr[4];
#pragma unroll
            for (int fm = 0; fm < 4; ++fm) af[fm] = ldfrag(At, wm * 64 + fm * 16 + c, ks * 4 + quad);
#pragma unroll
            for (int fn = 0; fn < 4; ++fn) bfr[fn] = ldfrag(Bt, wn * 64 + fn * 16 + c, ks * 4 + quad);
#pragma unroll
            for (int fm = 0; fm < 4; ++fm)
#pragma unroll
                for (int fn = 0; fn < 4; ++fn)
                    acc[fm][fn] = __builtin_amdgcn_mfma_f32_16x16x32_bf16(af[fm], bfr[fn], acc[fm][fn], 0, 0, 0);
        }
    }

    __syncthreads();   // k-loop LDS reads done; reuse smem as Ct
    if (z == 2) {
        // Ct[dd_local][rr_local]: lane holds 4 consecutive rr for fixed dd -> short4 write
#pragma unroll
        for (int fm = 0; fm < 4; ++fm)
#pragma unroll
            for (int fn = 0; fn < 4; ++fn) {
                int ddl = wn * 64 + fn * 16 + c;
                int rrl0 = wm * 64 + fm * 16 + quad * 4;
                short4 v4;
                v4.x = f2bf(acc[fm][fn][0]); v4.y = f2bf(acc[fm][fn][1]);
                v4.z = f2bf(acc[fm][fn][2]); v4.w = f2bf(acc[fm][fn][3]);
                *(short4*)(Ct + ddl * TSTRIDE + rrl0) = v4;
            }
    } else {
        const float sc = (z == 0) ? 0.125f : 1.0f;
#pragma unroll
        for (int fm = 0; fm < 4; ++fm)
#pragma unroll
            for (int fn = 0; fn < 4; ++fn) {
                int rrl0 = wm * 64 + fm * 16 + quad * 4;
                int ddl = wn * 64 + fn * 16 + c;
#pragma unroll
                for (int reg = 0; reg < 4; ++reg)
                    Ct[(rrl0 + reg) * TSTRIDE + ddl] = f2bf(acc[fm][fn][reg] * sc);
            }
    }
    __syncthreads();

    const int bb = row0 >> 10;  // whole 128-row block lies in one batch
#pragma unroll
    for (int it = 0; it < 8; ++it) {
        int row = it * 16 + (t >> 4);
        int ck = t & 15;
        bf16x8 v = *(const bf16x8*)(Ct + row * TSTRIDE + ck * 8);
        if (z == 2) {
            int gdd = col0 + row;                  // global col = Vt row
            int head = bb * 12 + (gdd >> 6);
            *(bf16x8*)(Vtg + ((size_t)head * 64 + (gdd & 63)) * 1024 + (row0 & 1023) + ck * 8) = v;
        } else {
            int rr = (row0 & 1023) + row;
            int gc = col0 + ck * 8;                // 8-short chunk never straddles a head
            int head = bb * 12 + (gc >> 6);
            short* dst = (z == 0) ? Qg : Kg;
            *(bf16x8*)(dst + ((size_t)head * 1024 + rr) * 64 + (gc & 63)) = v;
        }
    }
}

// ---------------- LSE pass (no-max online logsumexp; args are bounded) ----------------
// out[row] = out_sign * log( sum_col exp( A_row . B_col + bias_sign*bias[col] ) )
// A,B: per-head [1024,64] bf16. bias may be null.
__global__ __launch_bounds__(256) void lse_pass(
    const short* __restrict__ Aall, const short* __restrict__ Ball,
    const float* __restrict__ bias, float* __restrict__ outv,
    float bias_sign, float out_sign)
{
    __shared__ __align__(16) short At[128 * 64];
    __shared__ __align__(16) short Bt[128 * 64];
    __shared__ __align__(16) float biasl[1024];
    const int t = threadIdx.x;
    const int head = blockIdx.y;
    const int r0 = blockIdx.x * 128;
    const int lane = t & 63, w = t >> 6, quad = lane >> 4, c = lane & 15;
    const short* A = Aall + (size_t)head * 65536;
    const short* B = Ball + (size_t)head * 65536;

    stage_tile<4>(A + r0 * 64, 64, At, t);
    if (bias) ((float4*)biasl)[t] = ((const float4*)(bias + (size_t)head * 1024))[t];
    else      ((float4*)biasl)[t] = make_float4(0.f, 0.f, 0.f, 0.f);

    float lsum[2][4];
#pragma unroll
    for (int fm = 0; fm < 2; ++fm)
#pragma unroll
        for (int reg = 0; reg < 4; ++reg) lsum[fm][reg] = 0.f;

    for (int j0 = 0; j0 < 1024; j0 += 128) {
        __syncthreads();
        stage_tile<4>(B + j0 * 64, 64, Bt, t);
        __syncthreads();
        f32x4 sacc[2][8];
#pragma unroll
        for (int fm = 0; fm < 2; ++fm)
#pragma unroll
            for (int fn = 0; fn < 8; ++fn) sacc[fm][fn] = (f32x4){0.f, 0.f, 0.f, 0.f};
#pragma unroll
        for (int ks = 0; ks < 2; ++ks) {
            bf16x8 af[2], bfr[8];
#pragma unroll
            for (int fm = 0; fm < 2; ++fm) af[fm] = ldfrag(At, w * 32 + fm * 16 + c, ks * 4 + quad);
#pragma unroll
            for (int fn = 0; fn < 8; ++fn) bfr[fn] = ldfrag(Bt, fn * 16 + c, ks * 4 + quad);
#pragma unroll
            for (int fm = 0; fm < 2; ++fm)
#pragma unroll
                for (int fn = 0; fn < 8; ++fn)
                    sacc[fm][fn] = __builtin_amdgcn_mfma_f32_16x16x32_bf16(af[fm], bfr[fn], sacc[fm][fn], 0, 0, 0);
        }
#pragma unroll
        for (int fn = 0; fn < 8; ++fn) {
            float bv = biasl[j0 + fn * 16 + c] * bias_sign;
#pragma unroll
            for (int fm = 0; fm < 2; ++fm)
#pragma unroll
                for (int reg = 0; reg < 4; ++reg)
                    lsum[fm][reg] += __expf(sacc[fm][fn][reg] + bv);
        }
    }

#pragma unroll
    for (int fm = 0; fm < 2; ++fm)
#pragma unroll
        for (int reg = 0; reg < 4; ++reg) {
            float s = lsum[fm][reg];
            s += __shfl_xor(s, 1); s += __shfl_xor(s, 2);
            s += __shfl_xor(s, 4); s += __shfl_xor(s, 8);
            lsum[fm][reg] = s;
        }
    if (c == 0) {
#pragma unroll
        for (int fm = 0; fm < 2; ++fm)
#pragma unroll
            for (int reg = 0; reg < 4; ++reg)
                outv[(size_t)head * 1024 + r0 + w * 32 + fm * 16 + quad * 4 + reg] =
                    out_sign * __logf(lsum[fm][reg]);
    }
}

// ---------------- flash pass: ctx = (1/n) softmax_j(S+v1) @ V ----------------
__global__ __launch_bounds__(256) void flash_pass(
    const short* __restrict__ Qall, const short* __restrict__ Kall,
    const short* __restrict__ Vtall, const float* __restrict__ v1,
    short* __restrict__ ctx)
{
    __shared__ __align__(16) short Qt[128 * 64];
    __shared__ __align__(16) short Kt[64 * 64];
    __shared__ __align__(16) short Vtl[64 * 64];
    __shared__ __align__(16) short Pl[4][32 * 72];   // padded stride 72 shorts (144B)
    __shared__ __align__(16) float v1l[1024];
    const int t = threadIdx.x;
    const int head = blockIdx.y;
    const int r0 = blockIdx.x * 128;
    const int lane = t & 63, w = t >> 6, quad = lane >> 4, c = lane & 15;
    const short* Q = Qall + (size_t)head * 65536;
    const short* K = Kall + (size_t)head * 65536;
    const short* Vt = Vtall + (size_t)head * 65536;

    stage_tile<4>(Q + r0 * 64, 64, Qt, t);
    ((float4*)v1l)[t] = ((const float4*)(v1 + (size_t)head * 1024))[t];

    float lsum[2][4];
    f32x4 oacc[2][4];
#pragma unroll
    for (int fm = 0; fm < 2; ++fm)
#pragma unroll
        for (int x = 0; x < 4; ++x) { lsum[fm][x] = 0.f; oacc[fm][x] = (f32x4){0.f, 0.f, 0.f, 0.f}; }
    short* myP = Pl[w];

    for (int j0 = 0; j0 < 1024; j0 += 64) {
        __syncthreads();
        stage_tile<2>(K + j0 * 64, 64, Kt, t);
        stage_tile<2>(Vt + j0, 1024, Vtl, t);
        __syncthreads();
        // S strip: rows w*32..w*32+32, cols j0..j0+64
        f32x4 sacc[2][4];
#pragma unroll
        for (int fm = 0; fm < 2; ++fm)
#pragma unroll
            for (int fn = 0; fn < 4; ++fn) sacc[fm][fn] = (f32x4){0.f, 0.f, 0.f, 0.f};
#pragma unroll
        for (int ks = 0; ks < 2; ++ks) {
            bf16x8 af[2], bfr[4];
#pragma unroll
            for (int fm = 0; fm < 2; ++fm) af[fm] = ldfrag(Qt, w * 32 + fm * 16 + c, ks * 4 + quad);
#pragma unroll
            for (int fn = 0; fn < 4; ++fn) bfr[fn] = ldfrag(Kt, fn * 16 + c, ks * 4 + quad);
#pragma unroll
            for (int fm = 0; fm < 2; ++fm)
#pragma unroll
                for (int fn = 0; fn < 4; ++fn)
                    sacc[fm][fn] = __builtin_amdgcn_mfma_f32_16x16x32_bf16(af[fm], bfr[fn], sacc[fm][fn], 0, 0, 0);
        }
        // P = exp(S + v1), accumulate row sums, round-trip P through LDS (C->A layout)
#pragma unroll
        for (int fn = 0; fn < 4; ++fn) {
            float bv = v1l[j0 + fn * 16 + c];
#pragma unroll
            for (int fm = 0; fm < 2; ++fm)
#pragma unroll
                for (int reg = 0; reg < 4; ++reg) {
                    float p = __expf(sacc[fm][fn][reg] + bv);
                    lsum[fm][reg] += p;
                    myP[(fm * 16 + quad * 4 + reg) * 72 + fn * 16 + c] = f2bf(p);
                }
        }
        asm volatile("s_waitcnt lgkmcnt(0)" ::: "memory");
        // O += P @ V   (B-frag from Vt tile rows = dd)
#pragma unroll
        for (int ks2 = 0; ks2 < 2; ++ks2) {
            bf16x8 paf[2], vbf[4];
#pragma unroll
            for (int fm = 0; fm < 2; ++fm)
                paf[fm] = *(const bf16x8*)(myP + (fm * 16 + c) * 72 + ks2 * 32 + quad * 8);
#pragma unroll
            for (int fn = 0; fn < 4; ++fn) vbf[fn] = ldfrag(Vtl, fn * 16 + c, ks2 * 4 + quad);
#pragma unroll
            for (int fm = 0; fm < 2; ++fm)
#pragma unroll
                for (int fn = 0; fn < 4; ++fn)
                    oacc[fm][fn] = __builtin_amdgcn_mfma_f32_16x16x32_bf16(paf[fm], vbf[fn], oacc[fm][fn], 0, 0, 0);
        }
    }

#pragma unroll
    for (int fm = 0; fm < 2; ++fm)
#pragma unroll
        for (int reg = 0; reg < 4; ++reg) {
            float s = lsum[fm][reg];
            s += __shfl_xor(s, 1); s += __shfl_xor(s, 2);
            s += __shfl_xor(s, 4); s += __shfl_xor(s, 8);
            lsum[fm][reg] = 1.f / (1024.f * s);
        }
    const int bb = head / 12, hh = head % 12;
#pragma unroll
    for (int fm = 0; fm < 2; ++fm)
#pragma unroll
        for (int fn = 0; fn < 4; ++fn)
#pragma unroll
            for (int reg = 0; reg < 4; ++reg) {
                int rr = r0 + w * 32 + fm * 16 + quad * 4 + reg;
                ctx[((size_t)(bb * 1024 + rr)) * 768 + hh * 64 + fn * 16 + c] =
                    f2bf(oacc[fm][fn][reg] * lsum[fm][reg]);
            }
}

// ---------------- output projection ----------------
__global__ __launch_bounds__(256) void out_gemm(
    const short* __restrict__ ctxb, const short* __restrict__ wo,
    const float* __restrict__ bo, float* __restrict__ out)
{
    __shared__ __align__(16) short At[128 * 64];
    __shared__ __align__(16) short Bt[128 * 64];
    const int t = threadIdx.x;
    const int row0 = blockIdx.x * 128, col0 = blockIdx.y * 128;
    const int lane = t & 63, w = t >> 6, quad = lane >> 4, c = lane & 15;
    const int wm = w >> 1, wn = w & 1;

    f32x4 acc[4][4];
#pragma unroll
    for (int i = 0; i < 4; ++i)
#pragma unroll
        for (int j = 0; j < 4; ++j) acc[i][j] = (f32x4){0.f, 0.f, 0.f, 0.f};

    for (int k0 = 0; k0 < 768; k0 += 64) {
        __syncthreads();
        stage_tile<4>(ctxb + (size_t)row0 * 768 + k0, 768, At, t);
        stage_tile<4>(wo + (size_t)col0 * 768 + k0, 768, Bt, t);
        __syncthreads();
#pragma unroll
        for (int ks = 0; ks < 2; ++ks) {
            bf16x8 af[4], bfr[4];
#pragma unroll
            for (int fm = 0; fm < 4; ++fm) af[fm] = ldfrag(At, wm * 64 + fm * 16 + c, ks * 4 + quad);
#pragma unroll
            for (int fn = 0; fn < 4; ++fn) bfr[fn] = ldfrag(Bt, wn * 64 + fn * 16 + c, ks * 4 + quad);
#pragma unroll
            for (int fm = 0; fm < 4; ++fm)
#pragma unroll
                for (int fn = 0; fn < 4; ++fn)
                    acc[fm][fn] = __builtin_amdgcn_mfma_f32_16x16x32_bf16(af[fm], bfr[fn], acc[fm][fn], 0, 0, 0);
        }
    }
#pragma unroll
    for (int fm = 0; fm < 4; ++fm)
#pragma unroll
        for (int fn = 0; fn < 4; ++fn) {
            int gr0 = row0 + wm * 64 + fm * 16 + quad * 4;
            int gc = col0 + wn * 64 + fn * 16 + c;
            float b = bo[gc];
#pragma unroll
            for (int reg = 0; reg < 4; ++reg)
                out[(size_t)(gr0 + reg) * 768 + gc] = acc[fm][fn][reg] + b;
        }
}

extern "C" void kernel_launch(void* const* d_in, const int* in_sizes, int n_in,
                              void* d_out, int out_size, void* d_ws, size_t ws_size,
                              hipStream_t stream) {
    const float* x  = (const float*)d_in[0];
    const float* Wq = (const float*)d_in[1];
    const float* Wk = (const float*)d_in[2];
    const float* Wv = (const float*)d_in[3];
    const float* Wo = (const float*)d_in[4];
    const float* bo = (const float*)d_in[5];
    float* out = (float*)d_out;

    char* p = (char*)d_ws;
    short* xb  = (short*)p; p += (size_t)8192 * 768 * 2;
    short* wqb = (short*)p; p += (size_t)768 * 768 * 2;
    short* wkb = (short*)p; p += (size_t)768 * 768 * 2;
    short* wvb = (short*)p; p += (size_t)768 * 768 * 2;
    short* wob = (short*)p; p += (size_t)768 * 768 * 2;
    short* Qg  = (short*)p; p += (size_t)96 * 1024 * 64 * 2;
    short* Kg  = (short*)p; p += (size_t)96 * 1024 * 64 * 2;
    short* Vtg = (short*)p; p += (size_t)96 * 1024 * 64 * 2;
    float* r1  = (float*)p; p += (size_t)96 * 1024 * 4;
    float* v1  = (float*)p; p += (size_t)96 * 1024 * 4;
    short* ctx = (short*)p; p += (size_t)8192 * 768 * 2;

    cvt_all<<<6144 + 4 * 576, 256, 0, stream>>>(x, Wq, Wk, Wv, Wo, xb, wqb, wkb, wvb, wob);

    proj_gemm<<<dim3(64, 6, 3), 256, 0, stream>>>(xb, wqb, wkb, wvb, Qg, Kg, Vtg);

    // pass 1: r1[i] = +log sum_j exp(S[i,j])
    lse_pass<<<dim3(8, 96), 256, 0, stream>>>(Qg, Kg, nullptr, r1, 0.f, 1.f);
    // pass 2: v1[j] = -log sum_i exp(S[i,j] - r1[i])   (A=K, B=Q, bias=-r1)
    lse_pass<<<dim3(8, 96), 256, 0, stream>>>(Kg, Qg, r1, v1, -1.f, -1.f);

    flash_pass<<<dim3(8, 96), 256, 0, stream>>>(Qg, Kg, Vtg, v1, ctx);

    out_gemm<<<dim3(64, 6), 256, 0, stream>>>(ctx, wob, bo, out);
}

// Round 3
// 258.000 us; speedup vs baseline: 1.1665x; 1.0803x over previous
//
#include <hip/hip_runtime.h>

#define DEV __device__ __forceinline__

typedef __attribute__((ext_vector_type(4))) float f32x4;
typedef __attribute__((ext_vector_type(8))) short bf16x8;

// round-to-nearest-even f32 -> bf16 (bits in a short)
DEV short f2bf(float f) {
    union { float f; unsigned u; } v; v.f = f;
    unsigned r = (v.u + 0x7fffu + ((v.u >> 16) & 1u)) >> 16;
    return (short)r;
}

#ifndef __has_builtin
#define __has_builtin(x) 0
#endif
#if __has_builtin(__builtin_amdgcn_cvt_pk_bf16_f32)
DEV unsigned pkbf(float a, float b) {
    auto r = __builtin_amdgcn_cvt_pk_bf16_f32(a, b);
    union { __typeof__(r) v; unsigned u; } u; u.v = r; return u.u;
}
#else
DEV unsigned pkbf(float a, float b) {
    return (unsigned)(unsigned short)f2bf(a) | ((unsigned)(unsigned short)f2bf(b) << 16);
}
#endif

// async global->LDS, 16 bytes per lane. LDS dest = wave-uniform base + lane*16.
DEV void gl_lds16(const void* g, void* l) {
    __builtin_amdgcn_global_load_lds(
        (__attribute__((address_space(1))) void*)(g),
        (__attribute__((address_space(3))) void*)(l), 16, 0, 0);
}

// Stage ITERS*32 rows x 64 bf16 cols from row-major global (stride ldg shorts)
// into LDS tile with row stride 64 shorts. 16B chunks XOR-swizzled.
template <int ITERS>
DEV void stage_tile(const short* g, int ldg, short* lds, int t) {
    const int w = t >> 6;
#pragma unroll
    for (int it = 0; it < ITERS; ++it) {
        int row = it * 32 + (t >> 3);
        int cx = (t & 7) ^ ((t >> 3) & 7);
        gl_lds16(g + row * ldg + cx * 8, (char*)lds + it * 4096 + (w << 10));
    }
}

// read 8-bf16 fragment: chunk kc (0..7) of tile row r (row stride 64 shorts)
DEV bf16x8 ldfrag(const short* lds, int r, int kc) {
    return *(const bf16x8*)(lds + r * 64 + ((kc ^ (r & 7)) << 3));
}

// ---------------- conversion (all 5 tensors in one launch) ----------------
__global__ void cvt_all(const float* __restrict__ x,
                        const float* __restrict__ wq, const float* __restrict__ wk,
                        const float* __restrict__ wv, const float* __restrict__ wo,
                        short* __restrict__ xb,
                        short* __restrict__ wqb, short* __restrict__ wkb,
                        short* __restrict__ wvb, short* __restrict__ wob) {
    int b = blockIdx.x;
    const float* s; short* d; int i;
    if (b < 6144) {
        s = x; d = xb; i = b * 256 + threadIdx.x;
    } else {
        int r = b - 6144;
        int wi = r / 576, rem = r - wi * 576;
        s = (wi == 0) ? wq : (wi == 1) ? wk : (wi == 2) ? wv : wo;
        d = (wi == 0) ? wqb : (wi == 1) ? wkb : (wi == 2) ? wvb : wob;
        i = rem * 256 + threadIdx.x;
    }
    float4 v = ((const float4*)s)[i];
    short4 o;
    o.x = f2bf(v.x); o.y = f2bf(v.y); o.z = f2bf(v.z); o.w = f2bf(v.w);
    ((short4*)d)[i] = o;
}

// ---------------- QKV projection GEMM ----------------
// Q gets scale (1/8)*log2(e) folded so downstream exp/log run in base-2 domain.
#define TSTRIDE 136
__global__ __launch_bounds__(256) void proj_gemm(
    const short* __restrict__ xb,
    const short* __restrict__ wq, const short* __restrict__ wk, const short* __restrict__ wv,
    short* __restrict__ Qg, short* __restrict__ Kg, short* __restrict__ Vtg)
{
    __shared__ __align__(16) char smem[128 * TSTRIDE * 2];
    short* At = (short*)smem;
    short* Bt = (short*)(smem + 128 * 64 * 2);
    short* Ct = (short*)smem;
    const int t = threadIdx.x;
    const int z = blockIdx.z;
    const int row0 = blockIdx.x * 128, col0 = blockIdx.y * 128;
    const int lane = t & 63, w = t >> 6, quad = lane >> 4, c = lane & 15;
    const int wm = w >> 1, wn = w & 1;
    const short* W = (z == 0) ? wq : (z == 1) ? wk : wv;

    f32x4 acc[4][4];
#pragma unroll
    for (int i = 0; i < 4; ++i)
#pragma unroll
        for (int j = 0; j < 4; ++j) acc[i][j] = (f32x4){0.f, 0.f, 0.f, 0.f};

    for (int k0 = 0; k0 < 768; k0 += 64) {
        __syncthreads();
        stage_tile<4>(xb + (size_t)row0 * 768 + k0, 768, At, t);
        stage_tile<4>(W + (size_t)col0 * 768 + k0, 768, Bt, t);
        __syncthreads();
#pragma unroll
        for (int ks = 0; ks < 2; ++ks) {
            bf16x8 af[4], bfr[4];
#pragma unroll
            for (int fm = 0; fm < 4; ++fm) af[fm] = ldfrag(At, wm * 64 + fm * 16 + c, ks * 4 + quad);
#pragma unroll
            for (int fn = 0; fn < 4; ++fn) bfr[fn] = ldfrag(Bt, wn * 64 + fn * 16 + c, ks * 4 + quad);
#pragma unroll
            for (int fm = 0; fm < 4; ++fm)
#pragma unroll
                for (int fn = 0; fn < 4; ++fn)
                    acc[fm][fn] = __builtin_amdgcn_mfma_f32_16x16x32_bf16(af[fm], bfr[fn], acc[fm][fn], 0, 0, 0);
        }
    }

    __syncthreads();
    if (z == 2) {
#pragma unroll
        for (int fm = 0; fm < 4; ++fm)
#pragma unroll
            for (int fn = 0; fn < 4; ++fn) {
                int ddl = wn * 64 + fn * 16 + c;
                int rrl0 = wm * 64 + fm * 16 + quad * 4;
                short4 v4;
                v4.x = f2bf(acc[fm][fn][0]); v4.y = f2bf(acc[fm][fn][1]);
                v4.z = f2bf(acc[fm][fn][2]); v4.w = f2bf(acc[fm][fn][3]);
                *(short4*)(Ct + ddl * TSTRIDE + rrl0) = v4;
            }
    } else {
        const float sc = (z == 0) ? 0.125f * 1.4426950408889634f : 1.0f;
#pragma unroll
        for (int fm = 0; fm < 4; ++fm)
#pragma unroll
            for (int fn = 0; fn < 4; ++fn) {
                int rrl0 = wm * 64 + fm * 16 + quad * 4;
                int ddl = wn * 64 + fn * 16 + c;
#pragma unroll
                for (int reg = 0; reg < 4; ++reg)
                    Ct[(rrl0 + reg) * TSTRIDE + ddl] = f2bf(acc[fm][fn][reg] * sc);
            }
    }
    __syncthreads();

    const int bb = row0 >> 10;
#pragma unroll
    for (int it = 0; it < 8; ++it) {
        int row = it * 16 + (t >> 4);
        int ck = t & 15;
        bf16x8 v = *(const bf16x8*)(Ct + row * TSTRIDE + ck * 8);
        if (z == 2) {
            int gdd = col0 + row;
            int head = bb * 12 + (gdd >> 6);
            *(bf16x8*)(Vtg + ((size_t)head * 64 + (gdd & 63)) * 1024 + (row0 & 1023) + ck * 8) = v;
        } else {
            int rr = (row0 & 1023) + row;
            int gc = col0 + ck * 8;
            int head = bb * 12 + (gc >> 6);
            short* dst = (z == 0) ? Qg : Kg;
            *(bf16x8*)(dst + ((size_t)head * 1024 + rr) * 64 + (gc & 63)) = v;
        }
    }
}

// ---------------- LSE pass (base-2 domain, S^T layout) ----------------
// out[r] = out_sign * log2( sum_c exp2( A_r . B_c + bias2[c] ) ),  bias2 = bias_sign*bias
// Grid: 1-D 768, b%96 = head -> all 8 r-blocks of a head on one XCD.
__global__ __launch_bounds__(256) void lse_pass(
    const short* __restrict__ Aall, const short* __restrict__ Ball,
    const float* __restrict__ bias, float* __restrict__ outv,
    float bias_sign, float out_sign)
{
    __shared__ __align__(16) short At[128 * 64];
    __shared__ __align__(16) short Bt[128 * 64];
    __shared__ __align__(16) float biasl[1024];
    const int t = threadIdx.x;
    const int head = blockIdx.x % 96;
    const int r0 = (blockIdx.x / 96) * 128;
    const int lane = t & 63, w = t >> 6, quad = lane >> 4, c = lane & 15;
    const short* A = Aall + (size_t)head * 65536;
    const short* B = Ball + (size_t)head * 65536;

    stage_tile<4>(A + r0 * 64, 64, At, t);
    if (bias) {
        float4 v = ((const float4*)(bias + (size_t)head * 1024))[t];
        v.x *= bias_sign; v.y *= bias_sign; v.z *= bias_sign; v.w *= bias_sign;
        ((float4*)biasl)[t] = v;
    } else ((float4*)biasl)[t] = make_float4(0.f, 0.f, 0.f, 0.f);

    float lsum[2] = {0.f, 0.f};

    for (int j0 = 0; j0 < 1024; j0 += 128) {
        __syncthreads();
        stage_tile<4>(B + j0 * 64, 64, Bt, t);
        __syncthreads();
        // S^T: D[m = j (8 tiles)][n = i (2 tiles)]
        f32x4 sacc[8][2];
#pragma unroll
        for (int fm = 0; fm < 8; ++fm)
#pragma unroll
            for (int fn = 0; fn < 2; ++fn) sacc[fm][fn] = (f32x4){0.f, 0.f, 0.f, 0.f};
#pragma unroll
        for (int ks = 0; ks < 2; ++ks) {
            bf16x8 af[8], bfr[2];
#pragma unroll
            for (int fm = 0; fm < 8; ++fm) af[fm] = ldfrag(Bt, fm * 16 + c, ks * 4 + quad);
#pragma unroll
            for (int fn = 0; fn < 2; ++fn) bfr[fn] = ldfrag(At, w * 32 + fn * 16 + c, ks * 4 + quad);
#pragma unroll
            for (int fm = 0; fm < 8; ++fm)
#pragma unroll
                for (int fn = 0; fn < 2; ++fn)
                    sacc[fm][fn] = __builtin_amdgcn_mfma_f32_16x16x32_bf16(af[fm], bfr[fn], sacc[fm][fn], 0, 0, 0);
        }
#pragma unroll
        for (int fm = 0; fm < 8; ++fm) {
            float4 b4 = *(const float4*)(biasl + j0 + fm * 16 + quad * 4);
#pragma unroll
            for (int fn = 0; fn < 2; ++fn) {
                float p0 = __builtin_amdgcn_exp2f(sacc[fm][fn][0] + b4.x);
                float p1 = __builtin_amdgcn_exp2f(sacc[fm][fn][1] + b4.y);
                float p2 = __builtin_amdgcn_exp2f(sacc[fm][fn][2] + b4.z);
                float p3 = __builtin_amdgcn_exp2f(sacc[fm][fn][3] + b4.w);
                lsum[fn] += (p0 + p1) + (p2 + p3);
            }
        }
    }

    // lane holds row i = fn*16 + c; reduce across quads
#pragma unroll
    for (int fn = 0; fn < 2; ++fn) {
        float s = lsum[fn];
        s += __shfl_xor(s, 16); s += __shfl_xor(s, 32);
        lsum[fn] = s;
    }
    if (quad == 0 && w < 4) {
#pragma unroll
        for (int fn = 0; fn < 2; ++fn)
            outv[(size_t)head * 1024 + r0 + w * 32 + fn * 16 + c] =
                out_sign * __builtin_amdgcn_logf(lsum[fn]);
    }
}

// ---------------- flash pass: ctx = (1/n) softmax2_j(S2+v1_2) @ V ----------------
__global__ __launch_bounds__(256) void flash_pass(
    const short* __restrict__ Qall, const short* __restrict__ Kall,
    const short* __restrict__ Vtall, const float* __restrict__ v1,
    short* __restrict__ ctx)
{
    __shared__ __align__(16) short Qt[128 * 64];
    __shared__ __align__(16) short Kt[64 * 64];
    __shared__ __align__(16) short Vtl[64 * 64];
    __shared__ __align__(16) short Pl[4][32 * 72];   // P[i_local][j_local], stride 72
    __shared__ __align__(16) float v1l[1024];
    const int t = threadIdx.x;
    const int head = blockIdx.x % 96;
    const int r0 = (blockIdx.x / 96) * 128;
    const int lane = t & 63, w = t >> 6, quad = lane >> 4, c = lane & 15;
    const short* Q = Qall + (size_t)head * 65536;
    const short* K = Kall + (size_t)head * 65536;
    const short* Vt = Vtall + (size_t)head * 65536;

    stage_tile<4>(Q + r0 * 64, 64, Qt, t);
    ((float4*)v1l)[t] = ((const float4*)(v1 + (size_t)head * 1024))[t];

    float lsum[2] = {0.f, 0.f};
    f32x4 oacc[2][4];
#pragma unroll
    for (int fm = 0; fm < 2; ++fm)
#pragma unroll
        for (int fn = 0; fn < 4; ++fn) oacc[fm][fn] = (f32x4){0.f, 0.f, 0.f, 0.f};
    short* myP = Pl[w];

    for (int j0 = 0; j0 < 1024; j0 += 64) {
        __syncthreads();
        stage_tile<2>(K + j0 * 64, 64, Kt, t);
        stage_tile<2>(Vt + j0, 1024, Vtl, t);
        __syncthreads();
        // S^T strip: D[m = j (4 tiles)][n = i (2 tiles of wave's 32 rows)]
        f32x4 sacc[4][2];
#pragma unroll
        for (int fm = 0; fm < 4; ++fm)
#pragma unroll
            for (int fn = 0; fn < 2; ++fn) sacc[fm][fn] = (f32x4){0.f, 0.f, 0.f, 0.f};
#pragma unroll
        for (int ks = 0; ks < 2; ++ks) {
            bf16x8 af[4], bfr[2];
#pragma unroll
            for (int fm = 0; fm < 4; ++fm) af[fm] = ldfrag(Kt, fm * 16 + c, ks * 4 + quad);
#pragma unroll
            for (int fn = 0; fn < 2; ++fn) bfr[fn] = ldfrag(Qt, w * 32 + fn * 16 + c, ks * 4 + quad);
#pragma unroll
            for (int fm = 0; fm < 4; ++fm)
#pragma unroll
                for (int fn = 0; fn < 2; ++fn)
                    sacc[fm][fn] = __builtin_amdgcn_mfma_f32_16x16x32_bf16(af[fm], bfr[fn], sacc[fm][fn], 0, 0, 0);
        }
        // P = exp2(S2 + v1_2): lane holds fixed i = fn*16+c, 4 consecutive j -> packed b64 store
#pragma unroll
        for (int fm = 0; fm < 4; ++fm) {
            float4 b4 = *(const float4*)(v1l + j0 + fm * 16 + quad * 4);
#pragma unroll
            for (int fn = 0; fn < 2; ++fn) {
                float p0 = __builtin_amdgcn_exp2f(sacc[fm][fn][0] + b4.x);
                float p1 = __builtin_amdgcn_exp2f(sacc[fm][fn][1] + b4.y);
                float p2 = __builtin_amdgcn_exp2f(sacc[fm][fn][2] + b4.z);
                float p3 = __builtin_amdgcn_exp2f(sacc[fm][fn][3] + b4.w);
                lsum[fn] += (p0 + p1) + (p2 + p3);
                uint2 pk; pk.x = pkbf(p0, p1); pk.y = pkbf(p2, p3);
                *(uint2*)(myP + (fn * 16 + c) * 72 + fm * 16 + quad * 4) = pk;
            }
        }
        asm volatile("s_waitcnt lgkmcnt(0)" ::: "memory");
        // O += P @ V
#pragma unroll
        for (int ks2 = 0; ks2 < 2; ++ks2) {
            bf16x8 paf[2], vbf[4];
#pragma unroll
            for (int fm = 0; fm < 2; ++fm)
                paf[fm] = *(const bf16x8*)(myP + (fm * 16 + c) * 72 + ks2 * 32 + quad * 8);
#pragma unroll
            for (int fn = 0; fn < 4; ++fn) vbf[fn] = ldfrag(Vtl, fn * 16 + c, ks2 * 4 + quad);
#pragma unroll
            for (int fm = 0; fm < 2; ++fm)
#pragma unroll
                for (int fn = 0; fn < 4; ++fn)
                    oacc[fm][fn] = __builtin_amdgcn_mfma_f32_16x16x32_bf16(paf[fm], vbf[fn], oacc[fm][fn], 0, 0, 0);
        }
    }

    // row sums live at lane i = fn*16+c; reduce across quads
#pragma unroll
    for (int fn = 0; fn < 2; ++fn) {
        float s = lsum[fn];
        s += __shfl_xor(s, 16); s += __shfl_xor(s, 32);
        lsum[fn] = s;
    }
    const int bb = head / 12, hh = head % 12;
#pragma unroll
    for (int fm = 0; fm < 2; ++fm)
#pragma unroll
        for (int reg = 0; reg < 4; ++reg) {
            float nrm = __builtin_amdgcn_rcpf(1024.f * __shfl(lsum[fm], quad * 4 + reg, 64));
            int rr = r0 + w * 32 + fm * 16 + quad * 4 + reg;
#pragma unroll
            for (int fn = 0; fn < 4; ++fn)
                ctx[((size_t)(bb * 1024 + rr)) * 768 + hh * 64 + fn * 16 + c] =
                    f2bf(oacc[fm][fn][reg] * nrm);
        }
}

// ---------------- output projection ----------------
__global__ __launch_bounds__(256) void out_gemm(
    const short* __restrict__ ctxb, const short* __restrict__ wo,
    const float* __restrict__ bo, float* __restrict__ out)
{
    __shared__ __align__(16) short At[128 * 64];
    __shared__ __align__(16) short Bt[128 * 64];
    const int t = threadIdx.x;
    const int row0 = blockIdx.x * 128, col0 = blockIdx.y * 128;
    const int lane = t & 63, w = t >> 6, quad = lane >> 4, c = lane & 15;
    const int wm = w >> 1, wn = w & 1;

    f32x4 acc[4][4];
#pragma unroll
    for (int i = 0; i < 4; ++i)
#pragma unroll
        for (int j = 0; j < 4; ++j) acc[i][j] = (f32x4){0.f, 0.f, 0.f, 0.f};

    for (int k0 = 0; k0 < 768; k0 += 64) {
        __syncthreads();
        stage_tile<4>(ctxb + (size_t)row0 * 768 + k0, 768, At, t);
        stage_tile<4>(wo + (size_t)col0 * 768 + k0, 768, Bt, t);
        __syncthreads();
#pragma unroll
        for (int ks = 0; ks < 2; ++ks) {
            bf16x8 af[4], bfr[4];
#pragma unroll
            for (int fm = 0; fm < 4; ++fm) af[fm] = ldfrag(At, wm * 64 + fm * 16 + c, ks * 4 + quad);
#pragma unroll
            for (int fn = 0; fn < 4; ++fn) bfr[fn] = ldfrag(Bt, wn * 64 + fn * 16 + c, ks * 4 + quad);
#pragma unroll
            for (int fm = 0; fm < 4; ++fm)
#pragma unroll
                for (int fn = 0; fn < 4; ++fn)
                    acc[fm][fn] = __builtin_amdgcn_mfma_f32_16x16x32_bf16(af[fm], bfr[fn], acc[fm][fn], 0, 0, 0);
        }
    }
#pragma unroll
    for (int fm = 0; fm < 4; ++fm)
#pragma unroll
        for (int fn = 0; fn < 4; ++fn) {
            int gr0 = row0 + wm * 64 + fm * 16 + quad * 4;
            int gc = col0 + wn * 64 + fn * 16 + c;
            float b = bo[gc];
#pragma unroll
            for (int reg = 0; reg < 4; ++reg)
                out[(size_t)(gr0 + reg) * 768 + gc] = acc[fm][fn][reg] + b;
        }
}

extern "C" void kernel_launch(void* const* d_in, const int* in_sizes, int n_in,
                              void* d_out, int out_size, void* d_ws, size_t ws_size,
                              hipStream_t stream) {
    const float* x  = (const float*)d_in[0];
    const float* Wq = (const float*)d_in[1];
    const float* Wk = (const float*)d_in[2];
    const float* Wv = (const float*)d_in[3];
    const float* Wo = (const float*)d_in[4];
    const float* bo = (const float*)d_in[5];
    float* out = (float*)d_out;

    char* p = (char*)d_ws;
    short* xb  = (short*)p; p += (size_t)8192 * 768 * 2;
    short* wqb = (short*)p; p += (size_t)768 * 768 * 2;
    short* wkb = (short*)p; p += (size_t)768 * 768 * 2;
    short* wvb = (short*)p; p += (size_t)768 * 768 * 2;
    short* wob = (short*)p; p += (size_t)768 * 768 * 2;
    short* Qg  = (short*)p; p += (size_t)96 * 1024 * 64 * 2;
    short* Kg  = (short*)p; p += (size_t)96 * 1024 * 64 * 2;
    short* Vtg = (short*)p; p += (size_t)96 * 1024 * 64 * 2;
    float* r1  = (float*)p; p += (size_t)96 * 1024 * 4;
    float* v1  = (float*)p; p += (size_t)96 * 1024 * 4;
    short* ctx = (short*)p; p += (size_t)8192 * 768 * 2;

    cvt_all<<<6144 + 4 * 576, 256, 0, stream>>>(x, Wq, Wk, Wv, Wo, xb, wqb, wkb, wvb, wob);

    proj_gemm<<<dim3(64, 6, 3), 256, 0, stream>>>(xb, wqb, wkb, wvb, Qg, Kg, Vtg);

    // pass 1: r1_2[i] = +log2 sum_j exp2(S2[i,j])
    lse_pass<<<768, 256, 0, stream>>>(Qg, Kg, nullptr, r1, 0.f, 1.f);
    // pass 2: v1_2[j] = -log2 sum_i exp2(S2[i,j] - r1_2[i])
    lse_pass<<<768, 256, 0, stream>>>(Kg, Qg, r1, v1, -1.f, -1.f);

    flash_pass<<<768, 256, 0, stream>>>(Qg, Kg, Vtg, v1, ctx);

    out_gemm<<<dim3(64, 6), 256, 0, stream>>>(ctx, wob, bo, out);
}

// Round 4
// 244.867 us; speedup vs baseline: 1.2290x; 1.0536x over previous
//
#include <hip/hip_runtime.h>

#define DEV __device__ __forceinline__

typedef __attribute__((ext_vector_type(4))) float f32x4;
typedef __attribute__((ext_vector_type(8))) short bf16x8;
typedef __attribute__((ext_vector_type(4))) short bf16x4;

// round-to-nearest-even f32 -> bf16 (bits in a short)
DEV short f2bf(float f) {
    union { float f; unsigned u; } v; v.f = f;
    unsigned r = (v.u + 0x7fffu + ((v.u >> 16) & 1u)) >> 16;
    return (short)r;
}

#ifndef __has_builtin
#define __has_builtin(x) 0
#endif
#if __has_builtin(__builtin_amdgcn_cvt_pk_bf16_f32)
DEV unsigned pkbf(float a, float b) {
    auto r = __builtin_amdgcn_cvt_pk_bf16_f32(a, b);
    union { __typeof__(r) v; unsigned u; } u; u.v = r; return u.u;
}
#else
DEV unsigned pkbf(float a, float b) {
    return (unsigned)(unsigned short)f2bf(a) | ((unsigned)(unsigned short)f2bf(b) << 16);
}
#endif

// async global->LDS, 16 bytes per lane. LDS dest = wave-uniform base + lane*16.
DEV void gl_lds16(const void* g, void* l) {
    __builtin_amdgcn_global_load_lds(
        (__attribute__((address_space(1))) void*)(g),
        (__attribute__((address_space(3))) void*)(l), 16, 0, 0);
}

// Stage ITERS*32 rows x 64 bf16 cols from row-major global (stride ldg shorts)
// into LDS tile with row stride 64 shorts. 16B chunks XOR-swizzled.
template <int ITERS>
DEV void stage_tile(const short* g, int ldg, short* lds, int t) {
    const int w = t >> 6;
#pragma unroll
    for (int it = 0; it < ITERS; ++it) {
        int row = it * 32 + (t >> 3);
        int cx = (t & 7) ^ ((t >> 3) & 7);
        gl_lds16(g + row * ldg + cx * 8, (char*)lds + it * 4096 + (w << 10));
    }
}

// read 8-bf16 fragment: chunk kc (0..7) of tile row r (row stride 64 shorts)
DEV bf16x8 ldfrag(const short* lds, int r, int kc) {
    return *(const bf16x8*)(lds + r * 64 + ((kc ^ (r & 7)) << 3));
}

// read 4-bf16 group at j-offset o (multiple of 4) within tile row r
DEV bf16x4 ldv4(const short* lds, int r, int o) {
    int chunk = o >> 3, sub = o & 7;
    return *(const bf16x4*)(lds + r * 64 + ((chunk ^ (r & 7)) << 3) + sub);
}

// ---------------- conversion (all 5 tensors in one launch) ----------------
__global__ void cvt_all(const float* __restrict__ x,
                        const float* __restrict__ wq, const float* __restrict__ wk,
                        const float* __restrict__ wv, const float* __restrict__ wo,
                        short* __restrict__ xb,
                        short* __restrict__ wqb, short* __restrict__ wkb,
                        short* __restrict__ wvb, short* __restrict__ wob) {
    int b = blockIdx.x;
    const float* s; short* d; int i;
    if (b < 6144) {
        s = x; d = xb; i = b * 256 + threadIdx.x;
    } else {
        int r = b - 6144;
        int wi = r / 576, rem = r - wi * 576;
        s = (wi == 0) ? wq : (wi == 1) ? wk : (wi == 2) ? wv : wo;
        d = (wi == 0) ? wqb : (wi == 1) ? wkb : (wi == 2) ? wvb : wob;
        i = rem * 256 + threadIdx.x;
    }
    float4 v = ((const float4*)s)[i];
    short4 o;
    o.x = f2bf(v.x); o.y = f2bf(v.y); o.z = f2bf(v.z); o.w = f2bf(v.w);
    ((short4*)d)[i] = o;
}

// ---------------- QKV projection GEMM ----------------
// Q gets scale (1/8)*log2(e) folded so downstream exp/log run in base-2 domain.
#define TSTRIDE 136
__global__ __launch_bounds__(256) void proj_gemm(
    const short* __restrict__ xb,
    const short* __restrict__ wq, const short* __restrict__ wk, const short* __restrict__ wv,
    short* __restrict__ Qg, short* __restrict__ Kg, short* __restrict__ Vtg)
{
    __shared__ __align__(16) char smem[128 * TSTRIDE * 2];
    short* At = (short*)smem;
    short* Bt = (short*)(smem + 128 * 64 * 2);
    short* Ct = (short*)smem;
    const int t = threadIdx.x;
    const int z = blockIdx.z;
    const int row0 = blockIdx.x * 128, col0 = blockIdx.y * 128;
    const int lane = t & 63, w = t >> 6, quad = lane >> 4, c = lane & 15;
    const int wm = w >> 1, wn = w & 1;
    const short* W = (z == 0) ? wq : (z == 1) ? wk : wv;

    f32x4 acc[4][4];
#pragma unroll
    for (int i = 0; i < 4; ++i)
#pragma unroll
        for (int j = 0; j < 4; ++j) acc[i][j] = (f32x4){0.f, 0.f, 0.f, 0.f};

    for (int k0 = 0; k0 < 768; k0 += 64) {
        __syncthreads();
        stage_tile<4>(xb + (size_t)row0 * 768 + k0, 768, At, t);
        stage_tile<4>(W + (size_t)col0 * 768 + k0, 768, Bt, t);
        __syncthreads();
#pragma unroll
        for (int ks = 0; ks < 2; ++ks) {
            bf16x8 af[4], bfr[4];
#pragma unroll
            for (int fm = 0; fm < 4; ++fm) af[fm] = ldfrag(At, wm * 64 + fm * 16 + c, ks * 4 + quad);
#pragma unroll
            for (int fn = 0; fn < 4; ++fn) bfr[fn] = ldfrag(Bt, wn * 64 + fn * 16 + c, ks * 4 + quad);
#pragma unroll
            for (int fm = 0; fm < 4; ++fm)
#pragma unroll
                for (int fn = 0; fn < 4; ++fn)
                    acc[fm][fn] = __builtin_amdgcn_mfma_f32_16x16x32_bf16(af[fm], bfr[fn], acc[fm][fn], 0, 0, 0);
        }
    }

    __syncthreads();
    if (z == 2) {
#pragma unroll
        for (int fm = 0; fm < 4; ++fm)
#pragma unroll
            for (int fn = 0; fn < 4; ++fn) {
                int ddl = wn * 64 + fn * 16 + c;
                int rrl0 = wm * 64 + fm * 16 + quad * 4;
                short4 v4;
                v4.x = f2bf(acc[fm][fn][0]); v4.y = f2bf(acc[fm][fn][1]);
                v4.z = f2bf(acc[fm][fn][2]); v4.w = f2bf(acc[fm][fn][3]);
                *(short4*)(Ct + ddl * TSTRIDE + rrl0) = v4;
            }
    } else {
        const float sc = (z == 0) ? 0.125f * 1.4426950408889634f : 1.0f;
#pragma unroll
        for (int fm = 0; fm < 4; ++fm)
#pragma unroll
            for (int fn = 0; fn < 4; ++fn) {
                int rrl0 = wm * 64 + fm * 16 + quad * 4;
                int ddl = wn * 64 + fn * 16 + c;
#pragma unroll
                for (int reg = 0; reg < 4; ++reg)
                    Ct[(rrl0 + reg) * TSTRIDE + ddl] = f2bf(acc[fm][fn][reg] * sc);
            }
    }
    __syncthreads();

    const int bb = row0 >> 10;
#pragma unroll
    for (int it = 0; it < 8; ++it) {
        int row = it * 16 + (t >> 4);
        int ck = t & 15;
        bf16x8 v = *(const bf16x8*)(Ct + row * TSTRIDE + ck * 8);
        if (z == 2) {
            int gdd = col0 + row;
            int head = bb * 12 + (gdd >> 6);
            *(bf16x8*)(Vtg + ((size_t)head * 64 + (gdd & 63)) * 1024 + (row0 & 1023) + ck * 8) = v;
        } else {
            int rr = (row0 & 1023) + row;
            int gc = col0 + ck * 8;
            int head = bb * 12 + (gc >> 6);
            short* dst = (z == 0) ? Qg : Kg;
            *(bf16x8*)(dst + ((size_t)head * 1024 + rr) * 64 + (gc & 63)) = v;
        }
    }
}

// ---------------- LSE pass (base-2 domain, S^T layout) ----------------
__global__ __launch_bounds__(256) void lse_pass(
    const short* __restrict__ Aall, const short* __restrict__ Ball,
    const float* __restrict__ bias, float* __restrict__ outv,
    float bias_sign, float out_sign)
{
    __shared__ __align__(16) short At[128 * 64];
    __shared__ __align__(16) short Bt[128 * 64];
    __shared__ __align__(16) float biasl[1024];
    const int t = threadIdx.x;
    const int head = blockIdx.x % 96;
    const int r0 = (blockIdx.x / 96) * 128;
    const int lane = t & 63, w = t >> 6, quad = lane >> 4, c = lane & 15;
    const short* A = Aall + (size_t)head * 65536;
    const short* B = Ball + (size_t)head * 65536;

    stage_tile<4>(A + r0 * 64, 64, At, t);
    if (bias) {
        float4 v = ((const float4*)(bias + (size_t)head * 1024))[t];
        v.x *= bias_sign; v.y *= bias_sign; v.z *= bias_sign; v.w *= bias_sign;
        ((float4*)biasl)[t] = v;
    } else ((float4*)biasl)[t] = make_float4(0.f, 0.f, 0.f, 0.f);

    float lsum[2] = {0.f, 0.f};

    for (int j0 = 0; j0 < 1024; j0 += 128) {
        __syncthreads();
        stage_tile<4>(B + j0 * 64, 64, Bt, t);
        __syncthreads();
        f32x4 sacc[8][2];
#pragma unroll
        for (int fm = 0; fm < 8; ++fm)
#pragma unroll
            for (int fn = 0; fn < 2; ++fn) sacc[fm][fn] = (f32x4){0.f, 0.f, 0.f, 0.f};
#pragma unroll
        for (int ks = 0; ks < 2; ++ks) {
            bf16x8 af[8], bfr[2];
#pragma unroll
            for (int fm = 0; fm < 8; ++fm) af[fm] = ldfrag(Bt, fm * 16 + c, ks * 4 + quad);
#pragma unroll
            for (int fn = 0; fn < 2; ++fn) bfr[fn] = ldfrag(At, w * 32 + fn * 16 + c, ks * 4 + quad);
#pragma unroll
            for (int fm = 0; fm < 8; ++fm)
#pragma unroll
                for (int fn = 0; fn < 2; ++fn)
                    sacc[fm][fn] = __builtin_amdgcn_mfma_f32_16x16x32_bf16(af[fm], bfr[fn], sacc[fm][fn], 0, 0, 0);
        }
#pragma unroll
        for (int fm = 0; fm < 8; ++fm) {
            float4 b4 = *(const float4*)(biasl + j0 + fm * 16 + quad * 4);
#pragma unroll
            for (int fn = 0; fn < 2; ++fn) {
                float p0 = __builtin_amdgcn_exp2f(sacc[fm][fn][0] + b4.x);
                float p1 = __builtin_amdgcn_exp2f(sacc[fm][fn][1] + b4.y);
                float p2 = __builtin_amdgcn_exp2f(sacc[fm][fn][2] + b4.z);
                float p3 = __builtin_amdgcn_exp2f(sacc[fm][fn][3] + b4.w);
                lsum[fn] += (p0 + p1) + (p2 + p3);
            }
        }
    }

#pragma unroll
    for (int fn = 0; fn < 2; ++fn) {
        float s = lsum[fn];
        s += __shfl_xor(s, 16); s += __shfl_xor(s, 32);
        lsum[fn] = s;
    }
    if (quad == 0 && w < 4) {
#pragma unroll
        for (int fn = 0; fn < 2; ++fn)
            outv[(size_t)head * 1024 + r0 + w * 32 + fn * 16 + c] =
                out_sign * __builtin_amdgcn_logf(lsum[fn]);
    }
}

// ---------------- flash pass: ctx = (1/n) softmax2_j(S2+v1_2) @ V ----------------
// P never touches LDS: the MFMA k-slot bijection j = 32ks + 16(jj>>2) + 4quad + (jj&3)
// makes the lane's own packed exp2 outputs exactly the PV B-fragment; V A-frags use
// the same j-map via two ds_read_b64 from the swizzled Vt tile. Output is O^T.
__global__ __launch_bounds__(256, 4) void flash_pass(
    const short* __restrict__ Qall, const short* __restrict__ Kall,
    const short* __restrict__ Vtall, const float* __restrict__ v1,
    short* __restrict__ ctx)
{
    __shared__ __align__(16) short Qt[128 * 64];
    __shared__ __align__(16) short Kt[64 * 64];
    __shared__ __align__(16) short Vtl[64 * 64];
    __shared__ __align__(16) float v1l[1024];
    const int t = threadIdx.x;
    const int head = blockIdx.x % 96;
    const int r0 = (blockIdx.x / 96) * 128;
    const int lane = t & 63, w = t >> 6, quad = lane >> 4, c = lane & 15;
    const short* Q = Qall + (size_t)head * 65536;
    const short* K = Kall + (size_t)head * 65536;
    const short* Vt = Vtall + (size_t)head * 65536;

    stage_tile<4>(Q + r0 * 64, 64, Qt, t);
    ((float4*)v1l)[t] = ((const float4*)(v1 + (size_t)head * 1024))[t];

    float lsum[2] = {0.f, 0.f};
    f32x4 oacc[4][2];   // O^T tiles: m = d (4), n = i (2)
#pragma unroll
    for (int md = 0; md < 4; ++md)
#pragma unroll
        for (int ni = 0; ni < 2; ++ni) oacc[md][ni] = (f32x4){0.f, 0.f, 0.f, 0.f};

    for (int j0 = 0; j0 < 1024; j0 += 64) {
        __syncthreads();
        stage_tile<2>(K + j0 * 64, 64, Kt, t);
        stage_tile<2>(Vt + j0, 1024, Vtl, t);
        __syncthreads();
        // S^T strip: D[m = j (4 tiles)][n = i (2 tiles of wave's 32 rows)]
        f32x4 sacc[4][2];
#pragma unroll
        for (int fm = 0; fm < 4; ++fm)
#pragma unroll
            for (int fn = 0; fn < 2; ++fn) sacc[fm][fn] = (f32x4){0.f, 0.f, 0.f, 0.f};
#pragma unroll
        for (int ks = 0; ks < 2; ++ks) {
            bf16x8 af[4], bfr[2];
#pragma unroll
            for (int fm = 0; fm < 4; ++fm) af[fm] = ldfrag(Kt, fm * 16 + c, ks * 4 + quad);
#pragma unroll
            for (int fn = 0; fn < 2; ++fn) bfr[fn] = ldfrag(Qt, w * 32 + fn * 16 + c, ks * 4 + quad);
#pragma unroll
            for (int fm = 0; fm < 4; ++fm)
#pragma unroll
                for (int fn = 0; fn < 2; ++fn)
                    sacc[fm][fn] = __builtin_amdgcn_mfma_f32_16x16x32_bf16(af[fm], bfr[fn], sacc[fm][fn], 0, 0, 0);
        }
        // P = exp2(S2 + v1_2): lane holds P^T[j = fm*16+4quad+reg][i = fn*16+c]
        unsigned pk[4][2][2];   // [fm j-tile][fn i-tile][word]
#pragma unroll
        for (int fm = 0; fm < 4; ++fm) {
            float4 b4 = *(const float4*)(v1l + j0 + fm * 16 + quad * 4);
#pragma unroll
            for (int fn = 0; fn < 2; ++fn) {
                float p0 = __builtin_amdgcn_exp2f(sacc[fm][fn][0] + b4.x);
                float p1 = __builtin_amdgcn_exp2f(sacc[fm][fn][1] + b4.y);
                float p2 = __builtin_amdgcn_exp2f(sacc[fm][fn][2] + b4.z);
                float p3 = __builtin_amdgcn_exp2f(sacc[fm][fn][3] + b4.w);
                lsum[fn] += (p0 + p1) + (p2 + p3);
                pk[fm][fn][0] = pkbf(p0, p1);
                pk[fm][fn][1] = pkbf(p2, p3);
            }
        }
        // O^T += Vt · P^T under the shared k-slot map
#pragma unroll
        for (int ks = 0; ks < 2; ++ks) {
            bf16x8 vaf[4];
#pragma unroll
            for (int md = 0; md < 4; ++md) {
                union { bf16x8 v8; bf16x4 h[2]; } u;
                u.h[0] = ldv4(Vtl, md * 16 + c, ks * 32 + quad * 4);
                u.h[1] = ldv4(Vtl, md * 16 + c, ks * 32 + 16 + quad * 4);
                vaf[md] = u.v8;
            }
#pragma unroll
            for (int ni = 0; ni < 2; ++ni) {
                union { bf16x8 v8; unsigned u4[4]; } b;
                b.u4[0] = pk[2 * ks + 0][ni][0];
                b.u4[1] = pk[2 * ks + 0][ni][1];
                b.u4[2] = pk[2 * ks + 1][ni][0];
                b.u4[3] = pk[2 * ks + 1][ni][1];
#pragma unroll
                for (int md = 0; md < 4; ++md)
                    oacc[md][ni] = __builtin_amdgcn_mfma_f32_16x16x32_bf16(vaf[md], b.v8, oacc[md][ni], 0, 0, 0);
            }
        }
    }

    // row sums: lane's i = fn*16+c; reduce across quads -> every lane has its rows' sums
#pragma unroll
    for (int fn = 0; fn < 2; ++fn) {
        float s = lsum[fn];
        s += __shfl_xor(s, 16); s += __shfl_xor(s, 32);
        lsum[fn] = s;
    }
    const int bb = head / 12, hh = head % 12;
#pragma unroll
    for (int ni = 0; ni < 2; ++ni) {
        float nrm = __builtin_amdgcn_rcpf(1024.f * lsum[ni]);
        int rr = r0 + w * 32 + ni * 16 + c;
#pragma unroll
        for (int md = 0; md < 4; ++md) {
            short4 v4;
            v4.x = f2bf(oacc[md][ni][0] * nrm);
            v4.y = f2bf(oacc[md][ni][1] * nrm);
            v4.z = f2bf(oacc[md][ni][2] * nrm);
            v4.w = f2bf(oacc[md][ni][3] * nrm);
            *(short4*)(ctx + ((size_t)(bb * 1024 + rr)) * 768 + hh * 64 + md * 16 + quad * 4) = v4;
        }
    }
}

// ---------------- output projection ----------------
__global__ __launch_bounds__(256) void out_gemm(
    const short* __restrict__ ctxb, const short* __restrict__ wo,
    const float* __restrict__ bo, float* __restrict__ out)
{
    __shared__ __align__(16) short At[128 * 64];
    __shared__ __align__(16) short Bt[128 * 64];
    const int t = threadIdx.x;
    const int row0 = blockIdx.x * 128, col0 = blockIdx.y * 128;
    const int lane = t & 63, w = t >> 6, quad = lane >> 4, c = lane & 15;
    const int wm = w >> 1, wn = w & 1;

    f32x4 acc[4][4];
#pragma unroll
    for (int i = 0; i < 4; ++i)
#pragma unroll
        for (int j = 0; j < 4; ++j) acc[i][j] = (f32x4){0.f, 0.f, 0.f, 0.f};

    for (int k0 = 0; k0 < 768; k0 += 64) {
        __syncthreads();
        stage_tile<4>(ctxb + (size_t)row0 * 768 + k0, 768, At, t);
        stage_tile<4>(wo + (size_t)col0 * 768 + k0, 768, Bt, t);
        __syncthreads();
#pragma unroll
        for (int ks = 0; ks < 2; ++ks) {
            bf16x8 af[4], bfr[4];
#pragma unroll
            for (int fm = 0; fm < 4; ++fm) af[fm] = ldfrag(At, wm * 64 + fm * 16 + c, ks * 4 + quad);
#pragma unroll
            for (int fn = 0; fn < 4; ++fn) bfr[fn] = ldfrag(Bt, wn * 64 + fn * 16 + c, ks * 4 + quad);
#pragma unroll
            for (int fm = 0; fm < 4; ++fm)
#pragma unroll
                for (int fn = 0; fn < 4; ++fn)
                    acc[fm][fn] = __builtin_amdgcn_mfma_f32_16x16x32_bf16(af[fm], bfr[fn], acc[fm][fn], 0, 0, 0);
        }
    }
#pragma unroll
    for (int fm = 0; fm < 4; ++fm)
#pragma unroll
        for (int fn = 0; fn < 4; ++fn) {
            int gr0 = row0 + wm * 64 + fm * 16 + quad * 4;
            int gc = col0 + wn * 64 + fn * 16 + c;
            float b = bo[gc];
#pragma unroll
            for (int reg = 0; reg < 4; ++reg)
                out[(size_t)(gr0 + reg) * 768 + gc] = acc[fm][fn][reg] + b;
        }
}

extern "C" void kernel_launch(void* const* d_in, const int* in_sizes, int n_in,
                              void* d_out, int out_size, void* d_ws, size_t ws_size,
                              hipStream_t stream) {
    const float* x  = (const float*)d_in[0];
    const float* Wq = (const float*)d_in[1];
    const float* Wk = (const float*)d_in[2];
    const float* Wv = (const float*)d_in[3];
    const float* Wo = (const float*)d_in[4];
    const float* bo = (const float*)d_in[5];
    float* out = (float*)d_out;

    char* p = (char*)d_ws;
    short* xb  = (short*)p; p += (size_t)8192 * 768 * 2;
    short* wqb = (short*)p; p += (size_t)768 * 768 * 2;
    short* wkb = (short*)p; p += (size_t)768 * 768 * 2;
    short* wvb = (short*)p; p += (size_t)768 * 768 * 2;
    short* wob = (short*)p; p += (size_t)768 * 768 * 2;
    short* Qg  = (short*)p; p += (size_t)96 * 1024 * 64 * 2;
    short* Kg  = (short*)p; p += (size_t)96 * 1024 * 64 * 2;
    short* Vtg = (short*)p; p += (size_t)96 * 1024 * 64 * 2;
    float* r1  = (float*)p; p += (size_t)96 * 1024 * 4;
    float* v1  = (float*)p; p += (size_t)96 * 1024 * 4;
    short* ctx = (short*)p; p += (size_t)8192 * 768 * 2;

    cvt_all<<<6144 + 4 * 576, 256, 0, stream>>>(x, Wq, Wk, Wv, Wo, xb, wqb, wkb, wvb, wob);

    proj_gemm<<<dim3(64, 6, 3), 256, 0, stream>>>(xb, wqb, wkb, wvb, Qg, Kg, Vtg);

    // pass 1: r1_2[i] = +log2 sum_j exp2(S2[i,j])
    lse_pass<<<768, 256, 0, stream>>>(Qg, Kg, nullptr, r1, 0.f, 1.f);
    // pass 2: v1_2[j] = -log2 sum_i exp2(S2[i,j] - r1_2[i])
    lse_pass<<<768, 256, 0, stream>>>(Kg, Qg, r1, v1, -1.f, -1.f);

    flash_pass<<<768, 256, 0, stream>>>(Qg, Kg, Vtg, v1, ctx);

    out_gemm<<<dim3(64, 6), 256, 0, stream>>>(ctx, wob, bo, out);
}

// Round 5
// 242.127 us; speedup vs baseline: 1.2429x; 1.0113x over previous
//
#include <hip/hip_runtime.h>

#define DEV __device__ __forceinline__

typedef __attribute__((ext_vector_type(4))) float f32x4;
typedef __attribute__((ext_vector_type(16))) float f32x16;
typedef __attribute__((ext_vector_type(8))) short bf16x8;
typedef __attribute__((ext_vector_type(4))) short bf16x4;

// round-to-nearest-even f32 -> bf16 (bits in a short)
DEV short f2bf(float f) {
    union { float f; unsigned u; } v; v.f = f;
    unsigned r = (v.u + 0x7fffu + ((v.u >> 16) & 1u)) >> 16;
    return (short)r;
}

#ifndef __has_builtin
#define __has_builtin(x) 0
#endif
#if __has_builtin(__builtin_amdgcn_cvt_pk_bf16_f32)
DEV unsigned pkbf(float a, float b) {
    auto r = __builtin_amdgcn_cvt_pk_bf16_f32(a, b);
    union { __typeof__(r) v; unsigned u; } u; u.v = r; return u.u;
}
#else
DEV unsigned pkbf(float a, float b) {
    return (unsigned)(unsigned short)f2bf(a) | ((unsigned)(unsigned short)f2bf(b) << 16);
}
#endif

// async global->LDS, 16 bytes per lane. LDS dest = wave-uniform base + lane*16.
DEV void gl_lds16(const void* g, void* l) {
    __builtin_amdgcn_global_load_lds(
        (__attribute__((address_space(1))) void*)(g),
        (__attribute__((address_space(3))) void*)(l), 16, 0, 0);
}

// Stage ITERS*32 rows x 64 bf16 cols from row-major global (stride ldg shorts)
// into LDS tile with row stride 64 shorts. 16B chunks XOR-swizzled.
template <int ITERS>
DEV void stage_tile(const short* g, int ldg, short* lds, int t) {
    const int w = t >> 6;
#pragma unroll
    for (int it = 0; it < ITERS; ++it) {
        int row = it * 32 + (t >> 3);
        int cx = (t & 7) ^ ((t >> 3) & 7);
        gl_lds16(g + row * ldg + cx * 8, (char*)lds + it * 4096 + (w << 10));
    }
}

// read 8-bf16 fragment: chunk kc (0..7) of tile row r (row stride 64 shorts)
DEV bf16x8 ldfrag(const short* lds, int r, int kc) {
    return *(const bf16x8*)(lds + r * 64 + ((kc ^ (r & 7)) << 3));
}

// read 4-bf16 group at j-offset o (multiple of 4) within tile row r
DEV bf16x4 ldv4(const short* lds, int r, int o) {
    int chunk = o >> 3, sub = o & 7;
    return *(const bf16x4*)(lds + r * 64 + ((chunk ^ (r & 7)) << 3) + sub);
}

// ---------------- conversion (all 5 tensors in one launch) ----------------
__global__ void cvt_all(const float* __restrict__ x,
                        const float* __restrict__ wq, const float* __restrict__ wk,
                        const float* __restrict__ wv, const float* __restrict__ wo,
                        short* __restrict__ xb,
                        short* __restrict__ wqb, short* __restrict__ wkb,
                        short* __restrict__ wvb, short* __restrict__ wob) {
    int b = blockIdx.x;
    const float* s; short* d; int i;
    if (b < 6144) {
        s = x; d = xb; i = b * 256 + threadIdx.x;
    } else {
        int r = b - 6144;
        int wi = r / 576, rem = r - wi * 576;
        s = (wi == 0) ? wq : (wi == 1) ? wk : (wi == 2) ? wv : wo;
        d = (wi == 0) ? wqb : (wi == 1) ? wkb : (wi == 2) ? wvb : wob;
        i = rem * 256 + threadIdx.x;
    }
    float4 v = ((const float4*)s)[i];
    short4 o;
    o.x = f2bf(v.x); o.y = f2bf(v.y); o.z = f2bf(v.z); o.w = f2bf(v.w);
    ((short4*)d)[i] = o;
}

// ---------------- QKV projection GEMM (32x32x16 MFMA) ----------------
// Q gets scale (1/8)*log2(e) folded so downstream exp/log run in base-2 domain.
// 32x32 C-layout: col = lane&31, row = (reg&3) + 8*(reg>>2) + 4*(lane>>5).
// A/B frag: row/col = lane&31, k = (lane>>5)*8 + idx (8 contiguous).
#define TSTRIDE 136
__global__ __launch_bounds__(256, 4) void proj_gemm(
    const short* __restrict__ xb,
    const short* __restrict__ wq, const short* __restrict__ wk, const short* __restrict__ wv,
    short* __restrict__ Qg, short* __restrict__ Kg, short* __restrict__ Vtg)
{
    __shared__ __align__(16) char smem[128 * TSTRIDE * 2];
    short* At = (short*)smem;
    short* Bt = (short*)(smem + 128 * 64 * 2);
    short* Ct = (short*)smem;
    const int t = threadIdx.x;
    const int z = blockIdx.z;
    const int row0 = blockIdx.x * 128, col0 = blockIdx.y * 128;
    const int lane = t & 63, w = t >> 6;
    const int l31 = lane & 31, lh = lane >> 5;   // row/col within 32-tile, k-half
    const int wm = w >> 1, wn = w & 1;
    const short* W = (z == 0) ? wq : (z == 1) ? wk : wv;

    f32x16 acc[2][2];
#pragma unroll
    for (int i = 0; i < 2; ++i)
#pragma unroll
        for (int j = 0; j < 2; ++j) acc[i][j] = (f32x16)(0.f);

    for (int k0 = 0; k0 < 768; k0 += 64) {
        __syncthreads();
        stage_tile<4>(xb + (size_t)row0 * 768 + k0, 768, At, t);
        stage_tile<4>(W + (size_t)col0 * 768 + k0, 768, Bt, t);
        __syncthreads();
#pragma unroll
        for (int s = 0; s < 4; ++s) {        // k16 steps; chunk = s*2 + lh
            bf16x8 af[2], bfr[2];
#pragma unroll
            for (int tm = 0; tm < 2; ++tm) af[tm] = ldfrag(At, wm * 64 + tm * 32 + l31, s * 2 + lh);
#pragma unroll
            for (int tn = 0; tn < 2; ++tn) bfr[tn] = ldfrag(Bt, wn * 64 + tn * 32 + l31, s * 2 + lh);
#pragma unroll
            for (int tm = 0; tm < 2; ++tm)
#pragma unroll
                for (int tn = 0; tn < 2; ++tn)
                    acc[tm][tn] = __builtin_amdgcn_mfma_f32_32x32x16_bf16(af[tm], bfr[tn], acc[tm][tn], 0, 0, 0);
        }
    }

    __syncthreads();
    if (z == 2) {
        // transpose into Ct[dd][rr]; rows (reg&3) consecutive within each g=reg>>2 group
#pragma unroll
        for (int tm = 0; tm < 2; ++tm)
#pragma unroll
            for (int tn = 0; tn < 2; ++tn) {
                int ddl = wn * 64 + tn * 32 + l31;
#pragma unroll
                for (int g = 0; g < 4; ++g) {
                    int rrl = wm * 64 + tm * 32 + 8 * g + 4 * lh;
                    short4 v4;
                    v4.x = f2bf(acc[tm][tn][4 * g + 0]);
                    v4.y = f2bf(acc[tm][tn][4 * g + 1]);
                    v4.z = f2bf(acc[tm][tn][4 * g + 2]);
                    v4.w = f2bf(acc[tm][tn][4 * g + 3]);
                    *(short4*)(Ct + ddl * TSTRIDE + rrl) = v4;
                }
            }
    } else {
        const float sc = (z == 0) ? 0.125f * 1.4426950408889634f : 1.0f;
#pragma unroll
        for (int tm = 0; tm < 2; ++tm)
#pragma unroll
            for (int tn = 0; tn < 2; ++tn) {
                int ddl = wn * 64 + tn * 32 + l31;
#pragma unroll
                for (int reg = 0; reg < 16; ++reg) {
                    int rrl = wm * 64 + tm * 32 + (reg & 3) + 8 * (reg >> 2) + 4 * lh;
                    Ct[rrl * TSTRIDE + ddl] = f2bf(acc[tm][tn][reg] * sc);
                }
            }
    }
    __syncthreads();

    const int bb = row0 >> 10;
#pragma unroll
    for (int it = 0; it < 8; ++it) {
        int row = it * 16 + (t >> 4);
        int ck = t & 15;
        bf16x8 v = *(const bf16x8*)(Ct + row * TSTRIDE + ck * 8);
        if (z == 2) {
            int gdd = col0 + row;
            int head = bb * 12 + (gdd >> 6);
            *(bf16x8*)(Vtg + ((size_t)head * 64 + (gdd & 63)) * 1024 + (row0 & 1023) + ck * 8) = v;
        } else {
            int rr = (row0 & 1023) + row;
            int gc = col0 + ck * 8;
            int head = bb * 12 + (gc >> 6);
            short* dst = (z == 0) ? Qg : Kg;
            *(bf16x8*)(dst + ((size_t)head * 1024 + rr) * 64 + (gc & 63)) = v;
        }
    }
}

// ---------------- LSE pass (base-2 domain, S^T layout) ----------------
__global__ __launch_bounds__(256) void lse_pass(
    const short* __restrict__ Aall, const short* __restrict__ Ball,
    const float* __restrict__ bias, float* __restrict__ outv,
    float bias_sign, float out_sign)
{
    __shared__ __align__(16) short At[128 * 64];
    __shared__ __align__(16) short Bt[128 * 64];
    __shared__ __align__(16) float biasl[1024];
    const int t = threadIdx.x;
    const int head = blockIdx.x % 96;
    const int r0 = (blockIdx.x / 96) * 128;
    const int lane = t & 63, w = t >> 6, quad = lane >> 4, c = lane & 15;
    const short* A = Aall + (size_t)head * 65536;
    const short* B = Ball + (size_t)head * 65536;

    stage_tile<4>(A + r0 * 64, 64, At, t);
    if (bias) {
        float4 v = ((const float4*)(bias + (size_t)head * 1024))[t];
        v.x *= bias_sign; v.y *= bias_sign; v.z *= bias_sign; v.w *= bias_sign;
        ((float4*)biasl)[t] = v;
    } else ((float4*)biasl)[t] = make_float4(0.f, 0.f, 0.f, 0.f);

    float lsum[2] = {0.f, 0.f};

    for (int j0 = 0; j0 < 1024; j0 += 128) {
        __syncthreads();
        stage_tile<4>(B + j0 * 64, 64, Bt, t);
        __syncthreads();
        f32x4 sacc[8][2];
#pragma unroll
        for (int fm = 0; fm < 8; ++fm)
#pragma unroll
            for (int fn = 0; fn < 2; ++fn) sacc[fm][fn] = (f32x4){0.f, 0.f, 0.f, 0.f};
#pragma unroll
        for (int ks = 0; ks < 2; ++ks) {
            bf16x8 af[8], bfr[2];
#pragma unroll
            for (int fm = 0; fm < 8; ++fm) af[fm] = ldfrag(Bt, fm * 16 + c, ks * 4 + quad);
#pragma unroll
            for (int fn = 0; fn < 2; ++fn) bfr[fn] = ldfrag(At, w * 32 + fn * 16 + c, ks * 4 + quad);
#pragma unroll
            for (int fm = 0; fm < 8; ++fm)
#pragma unroll
                for (int fn = 0; fn < 2; ++fn)
                    sacc[fm][fn] = __builtin_amdgcn_mfma_f32_16x16x32_bf16(af[fm], bfr[fn], sacc[fm][fn], 0, 0, 0);
        }
#pragma unroll
        for (int fm = 0; fm < 8; ++fm) {
            float4 b4 = *(const float4*)(biasl + j0 + fm * 16 + quad * 4);
#pragma unroll
            for (int fn = 0; fn < 2; ++fn) {
                float p0 = __builtin_amdgcn_exp2f(sacc[fm][fn][0] + b4.x);
                float p1 = __builtin_amdgcn_exp2f(sacc[fm][fn][1] + b4.y);
                float p2 = __builtin_amdgcn_exp2f(sacc[fm][fn][2] + b4.z);
                float p3 = __builtin_amdgcn_exp2f(sacc[fm][fn][3] + b4.w);
                lsum[fn] += (p0 + p1) + (p2 + p3);
            }
        }
    }

#pragma unroll
    for (int fn = 0; fn < 2; ++fn) {
        float s = lsum[fn];
        s += __shfl_xor(s, 16); s += __shfl_xor(s, 32);
        lsum[fn] = s;
    }
    if (quad == 0 && w < 4) {
#pragma unroll
        for (int fn = 0; fn < 2; ++fn)
            outv[(size_t)head * 1024 + r0 + w * 32 + fn * 16 + c] =
                out_sign * __builtin_amdgcn_logf(lsum[fn]);
    }
}

// ---------------- flash pass: ctx = (1/n) softmax2_j(S2+v1_2) @ V ----------------
// P never touches LDS (k-slot bijection; see R3 notes). Output is O^T.
__global__ __launch_bounds__(256, 4) void flash_pass(
    const short* __restrict__ Qall, const short* __restrict__ Kall,
    const short* __restrict__ Vtall, const float* __restrict__ v1,
    short* __restrict__ ctx)
{
    __shared__ __align__(16) short Qt[128 * 64];
    __shared__ __align__(16) short Kt[64 * 64];
    __shared__ __align__(16) short Vtl[64 * 64];
    __shared__ __align__(16) float v1l[1024];
    const int t = threadIdx.x;
    const int head = blockIdx.x % 96;
    const int r0 = (blockIdx.x / 96) * 128;
    const int lane = t & 63, w = t >> 6, quad = lane >> 4, c = lane & 15;
    const short* Q = Qall + (size_t)head * 65536;
    const short* K = Kall + (size_t)head * 65536;
    const short* Vt = Vtall + (size_t)head * 65536;

    stage_tile<4>(Q + r0 * 64, 64, Qt, t);
    ((float4*)v1l)[t] = ((const float4*)(v1 + (size_t)head * 1024))[t];

    float lsum[2] = {0.f, 0.f};
    f32x4 oacc[4][2];   // O^T tiles: m = d (4), n = i (2)
#pragma unroll
    for (int md = 0; md < 4; ++md)
#pragma unroll
        for (int ni = 0; ni < 2; ++ni) oacc[md][ni] = (f32x4){0.f, 0.f, 0.f, 0.f};

    for (int j0 = 0; j0 < 1024; j0 += 64) {
        __syncthreads();
        stage_tile<2>(K + j0 * 64, 64, Kt, t);
        stage_tile<2>(Vt + j0, 1024, Vtl, t);
        __syncthreads();
        f32x4 sacc[4][2];
#pragma unroll
        for (int fm = 0; fm < 4; ++fm)
#pragma unroll
            for (int fn = 0; fn < 2; ++fn) sacc[fm][fn] = (f32x4){0.f, 0.f, 0.f, 0.f};
#pragma unroll
        for (int ks = 0; ks < 2; ++ks) {
            bf16x8 af[4], bfr[2];
#pragma unroll
            for (int fm = 0; fm < 4; ++fm) af[fm] = ldfrag(Kt, fm * 16 + c, ks * 4 + quad);
#pragma unroll
            for (int fn = 0; fn < 2; ++fn) bfr[fn] = ldfrag(Qt, w * 32 + fn * 16 + c, ks * 4 + quad);
#pragma unroll
            for (int fm = 0; fm < 4; ++fm)
#pragma unroll
                for (int fn = 0; fn < 2; ++fn)
                    sacc[fm][fn] = __builtin_amdgcn_mfma_f32_16x16x32_bf16(af[fm], bfr[fn], sacc[fm][fn], 0, 0, 0);
        }
        unsigned pk[4][2][2];
#pragma unroll
        for (int fm = 0; fm < 4; ++fm) {
            float4 b4 = *(const float4*)(v1l + j0 + fm * 16 + quad * 4);
#pragma unroll
            for (int fn = 0; fn < 2; ++fn) {
                float p0 = __builtin_amdgcn_exp2f(sacc[fm][fn][0] + b4.x);
                float p1 = __builtin_amdgcn_exp2f(sacc[fm][fn][1] + b4.y);
                float p2 = __builtin_amdgcn_exp2f(sacc[fm][fn][2] + b4.z);
                float p3 = __builtin_amdgcn_exp2f(sacc[fm][fn][3] + b4.w);
                lsum[fn] += (p0 + p1) + (p2 + p3);
                pk[fm][fn][0] = pkbf(p0, p1);
                pk[fm][fn][1] = pkbf(p2, p3);
            }
        }
#pragma unroll
        for (int ks = 0; ks < 2; ++ks) {
            bf16x8 vaf[4];
#pragma unroll
            for (int md = 0; md < 4; ++md) {
                union { bf16x8 v8; bf16x4 h[2]; } u;
                u.h[0] = ldv4(Vtl, md * 16 + c, ks * 32 + quad * 4);
                u.h[1] = ldv4(Vtl, md * 16 + c, ks * 32 + 16 + quad * 4);
                vaf[md] = u.v8;
            }
#pragma unroll
            for (int ni = 0; ni < 2; ++ni) {
                union { bf16x8 v8; unsigned u4[4]; } b;
                b.u4[0] = pk[2 * ks + 0][ni][0];
                b.u4[1] = pk[2 * ks + 0][ni][1];
                b.u4[2] = pk[2 * ks + 1][ni][0];
                b.u4[3] = pk[2 * ks + 1][ni][1];
#pragma unroll
                for (int md = 0; md < 4; ++md)
                    oacc[md][ni] = __builtin_amdgcn_mfma_f32_16x16x32_bf16(vaf[md], b.v8, oacc[md][ni], 0, 0, 0);
            }
        }
    }

#pragma unroll
    for (int fn = 0; fn < 2; ++fn) {
        float s = lsum[fn];
        s += __shfl_xor(s, 16); s += __shfl_xor(s, 32);
        lsum[fn] = s;
    }
    const int bb = head / 12, hh = head % 12;
#pragma unroll
    for (int ni = 0; ni < 2; ++ni) {
        float nrm = __builtin_amdgcn_rcpf(1024.f * lsum[ni]);
        int rr = r0 + w * 32 + ni * 16 + c;
#pragma unroll
        for (int md = 0; md < 4; ++md) {
            short4 v4;
            v4.x = f2bf(oacc[md][ni][0] * nrm);
            v4.y = f2bf(oacc[md][ni][1] * nrm);
            v4.z = f2bf(oacc[md][ni][2] * nrm);
            v4.w = f2bf(oacc[md][ni][3] * nrm);
            *(short4*)(ctx + ((size_t)(bb * 1024 + rr)) * 768 + hh * 64 + md * 16 + quad * 4) = v4;
        }
    }
}

// ---------------- output projection (32x32x16 MFMA) ----------------
__global__ __launch_bounds__(256, 4) void out_gemm(
    const short* __restrict__ ctxb, const short* __restrict__ wo,
    const float* __restrict__ bo, float* __restrict__ out)
{
    __shared__ __align__(16) short At[128 * 64];
    __shared__ __align__(16) short Bt[128 * 64];
    const int t = threadIdx.x;
    const int row0 = blockIdx.x * 128, col0 = blockIdx.y * 128;
    const int lane = t & 63, w = t >> 6;
    const int l31 = lane & 31, lh = lane >> 5;
    const int wm = w >> 1, wn = w & 1;

    f32x16 acc[2][2];
#pragma unroll
    for (int i = 0; i < 2; ++i)
#pragma unroll
        for (int j = 0; j < 2; ++j) acc[i][j] = (f32x16)(0.f);

    for (int k0 = 0; k0 < 768; k0 += 64) {
        __syncthreads();
        stage_tile<4>(ctxb + (size_t)row0 * 768 + k0, 768, At, t);
        stage_tile<4>(wo + (size_t)col0 * 768 + k0, 768, Bt, t);
        __syncthreads();
#pragma unroll
        for (int s = 0; s < 4; ++s) {
            bf16x8 af[2], bfr[2];
#pragma unroll
            for (int tm = 0; tm < 2; ++tm) af[tm] = ldfrag(At, wm * 64 + tm * 32 + l31, s * 2 + lh);
#pragma unroll
            for (int tn = 0; tn < 2; ++tn) bfr[tn] = ldfrag(Bt, wn * 64 + tn * 32 + l31, s * 2 + lh);
#pragma unroll
            for (int tm = 0; tm < 2; ++tm)
#pragma unroll
                for (int tn = 0; tn < 2; ++tn)
                    acc[tm][tn] = __builtin_amdgcn_mfma_f32_32x32x16_bf16(af[tm], bfr[tn], acc[tm][tn], 0, 0, 0);
        }
    }
#pragma unroll
    for (int tm = 0; tm < 2; ++tm)
#pragma unroll
        for (int tn = 0; tn < 2; ++tn) {
            int gc = col0 + wn * 64 + tn * 32 + l31;
            float b = bo[gc];
#pragma unroll
            for (int reg = 0; reg < 16; ++reg) {
                int gr = row0 + wm * 64 + tm * 32 + (reg & 3) + 8 * (reg >> 2) + 4 * lh;
                out[(size_t)gr * 768 + gc] = acc[tm][tn][reg] + b;
            }
        }
}

extern "C" void kernel_launch(void* const* d_in, const int* in_sizes, int n_in,
                              void* d_out, int out_size, void* d_ws, size_t ws_size,
                              hipStream_t stream) {
    const float* x  = (const float*)d_in[0];
    const float* Wq = (const float*)d_in[1];
    const float* Wk = (const float*)d_in[2];
    const float* Wv = (const float*)d_in[3];
    const float* Wo = (const float*)d_in[4];
    const float* bo = (const float*)d_in[5];
    float* out = (float*)d_out;

    char* p = (char*)d_ws;
    short* xb  = (short*)p; p += (size_t)8192 * 768 * 2;
    short* wqb = (short*)p; p += (size_t)768 * 768 * 2;
    short* wkb = (short*)p; p += (size_t)768 * 768 * 2;
    short* wvb = (short*)p; p += (size_t)768 * 768 * 2;
    short* wob = (short*)p; p += (size_t)768 * 768 * 2;
    short* Qg  = (short*)p; p += (size_t)96 * 1024 * 64 * 2;
    short* Kg  = (short*)p; p += (size_t)96 * 1024 * 64 * 2;
    short* Vtg = (short*)p; p += (size_t)96 * 1024 * 64 * 2;
    float* r1  = (float*)p; p += (size_t)96 * 1024 * 4;
    float* v1  = (float*)p; p += (size_t)96 * 1024 * 4;
    short* ctx = (short*)p; p += (size_t)8192 * 768 * 2;

    cvt_all<<<6144 + 4 * 576, 256, 0, stream>>>(x, Wq, Wk, Wv, Wo, xb, wqb, wkb, wvb, wob);

    proj_gemm<<<dim3(64, 6, 3), 256, 0, stream>>>(xb, wqb, wkb, wvb, Qg, Kg, Vtg);

    // pass 1: r1_2[i] = +log2 sum_j exp2(S2[i,j])
    lse_pass<<<768, 256, 0, stream>>>(Qg, Kg, nullptr, r1, 0.f, 1.f);
    // pass 2: v1_2[j] = -log2 sum_i exp2(S2[i,j] - r1_2[i])
    lse_pass<<<768, 256, 0, stream>>>(Kg, Qg, r1, v1, -1.f, -1.f);

    flash_pass<<<768, 256, 0, stream>>>(Qg, Kg, Vtg, v1, ctx);

    out_gemm<<<dim3(64, 6), 256, 0, stream>>>(ctx, wob, bo, out);
}

// Round 6
// 232.431 us; speedup vs baseline: 1.2948x; 1.0417x over previous
//
#include <hip/hip_runtime.h>

#define DEV __device__ __forceinline__

typedef __attribute__((ext_vector_type(4))) float f32x4;
typedef __attribute__((ext_vector_type(16))) float f32x16;
typedef __attribute__((ext_vector_type(8))) short bf16x8;
typedef __attribute__((ext_vector_type(4))) short bf16x4;

// round-to-nearest-even f32 -> bf16 (bits in a short)
DEV short f2bf(float f) {
    union { float f; unsigned u; } v; v.f = f;
    unsigned r = (v.u + 0x7fffu + ((v.u >> 16) & 1u)) >> 16;
    return (short)r;
}

#ifndef __has_builtin
#define __has_builtin(x) 0
#endif
#if __has_builtin(__builtin_amdgcn_cvt_pk_bf16_f32)
DEV unsigned pkbf(float a, float b) {
    auto r = __builtin_amdgcn_cvt_pk_bf16_f32(a, b);
    union { __typeof__(r) v; unsigned u; } u; u.v = r; return u.u;
}
#else
DEV unsigned pkbf(float a, float b) {
    return (unsigned)(unsigned short)f2bf(a) | ((unsigned)(unsigned short)f2bf(b) << 16);
}
#endif

// async global->LDS, 16 bytes per lane. LDS dest = wave-uniform base + lane*16.
DEV void gl_lds16(const void* g, void* l) {
    __builtin_amdgcn_global_load_lds(
        (__attribute__((address_space(1))) void*)(g),
        (__attribute__((address_space(3))) void*)(l), 16, 0, 0);
}

// Stage ITERS*32 rows x 64 bf16 cols from row-major global (stride ldg shorts)
// into LDS tile with row stride 64 shorts. 16B chunks XOR-swizzled.
template <int ITERS>
DEV void stage_tile(const short* g, int ldg, short* lds, int t) {
    const int w = t >> 6;
#pragma unroll
    for (int it = 0; it < ITERS; ++it) {
        int row = it * 32 + (t >> 3);
        int cx = (t & 7) ^ ((t >> 3) & 7);
        gl_lds16(g + row * ldg + cx * 8, (char*)lds + it * 4096 + (w << 10));
    }
}

// read 8-bf16 fragment: chunk kc (0..7) of tile row r (row stride 64 shorts)
DEV bf16x8 ldfrag(const short* lds, int r, int kc) {
    return *(const bf16x8*)(lds + r * 64 + ((kc ^ (r & 7)) << 3));
}

// read 4-bf16 group at j-offset o (multiple of 4) within tile row r
DEV bf16x4 ldv4(const short* lds, int r, int o) {
    int chunk = o >> 3, sub = o & 7;
    return *(const bf16x4*)(lds + r * 64 + ((chunk ^ (r & 7)) << 3) + sub);
}

// ---------------- conversion (all 5 tensors in one launch) ----------------
__global__ void cvt_all(const float* __restrict__ x,
                        const float* __restrict__ wq, const float* __restrict__ wk,
                        const float* __restrict__ wv, const float* __restrict__ wo,
                        short* __restrict__ xb,
                        short* __restrict__ wqb, short* __restrict__ wkb,
                        short* __restrict__ wvb, short* __restrict__ wob) {
    int b = blockIdx.x;
    const float* s; short* d; int i;
    if (b < 6144) {
        s = x; d = xb; i = b * 256 + threadIdx.x;
    } else {
        int r = b - 6144;
        int wi = r / 576, rem = r - wi * 576;
        s = (wi == 0) ? wq : (wi == 1) ? wk : (wi == 2) ? wv : wo;
        d = (wi == 0) ? wqb : (wi == 1) ? wkb : (wi == 2) ? wvb : wob;
        i = rem * 256 + threadIdx.x;
    }
    float4 v = ((const float4*)s)[i];
    short4 o;
    o.x = f2bf(v.x); o.y = f2bf(v.y); o.z = f2bf(v.z); o.w = f2bf(v.w);
    ((short4*)d)[i] = o;
}

// ---------------- QKV projection GEMM (32x32x16 MFMA) ----------------
#define TSTRIDE 136
__global__ __launch_bounds__(256, 4) void proj_gemm(
    const short* __restrict__ xb,
    const short* __restrict__ wq, const short* __restrict__ wk, const short* __restrict__ wv,
    short* __restrict__ Qg, short* __restrict__ Kg, short* __restrict__ Vtg)
{
    __shared__ __align__(16) char smem[128 * TSTRIDE * 2];
    short* At = (short*)smem;
    short* Bt = (short*)(smem + 128 * 64 * 2);
    short* Ct = (short*)smem;
    const int t = threadIdx.x;
    const int z = blockIdx.z;
    const int row0 = blockIdx.x * 128, col0 = blockIdx.y * 128;
    const int lane = t & 63, w = t >> 6;
    const int l31 = lane & 31, lh = lane >> 5;
    const int wm = w >> 1, wn = w & 1;
    const short* W = (z == 0) ? wq : (z == 1) ? wk : wv;

    f32x16 acc[2][2];
#pragma unroll
    for (int i = 0; i < 2; ++i)
#pragma unroll
        for (int j = 0; j < 2; ++j) acc[i][j] = (f32x16)(0.f);

    for (int k0 = 0; k0 < 768; k0 += 64) {
        __syncthreads();
        stage_tile<4>(xb + (size_t)row0 * 768 + k0, 768, At, t);
        stage_tile<4>(W + (size_t)col0 * 768 + k0, 768, Bt, t);
        __syncthreads();
#pragma unroll
        for (int s = 0; s < 4; ++s) {
            bf16x8 af[2], bfr[2];
#pragma unroll
            for (int tm = 0; tm < 2; ++tm) af[tm] = ldfrag(At, wm * 64 + tm * 32 + l31, s * 2 + lh);
#pragma unroll
            for (int tn = 0; tn < 2; ++tn) bfr[tn] = ldfrag(Bt, wn * 64 + tn * 32 + l31, s * 2 + lh);
#pragma unroll
            for (int tm = 0; tm < 2; ++tm)
#pragma unroll
                for (int tn = 0; tn < 2; ++tn)
                    acc[tm][tn] = __builtin_amdgcn_mfma_f32_32x32x16_bf16(af[tm], bfr[tn], acc[tm][tn], 0, 0, 0);
        }
    }

    __syncthreads();
    if (z == 2) {
#pragma unroll
        for (int tm = 0; tm < 2; ++tm)
#pragma unroll
            for (int tn = 0; tn < 2; ++tn) {
                int ddl = wn * 64 + tn * 32 + l31;
#pragma unroll
                for (int g = 0; g < 4; ++g) {
                    int rrl = wm * 64 + tm * 32 + 8 * g + 4 * lh;
                    short4 v4;
                    v4.x = f2bf(acc[tm][tn][4 * g + 0]);
                    v4.y = f2bf(acc[tm][tn][4 * g + 1]);
                    v4.z = f2bf(acc[tm][tn][4 * g + 2]);
                    v4.w = f2bf(acc[tm][tn][4 * g + 3]);
                    *(short4*)(Ct + ddl * TSTRIDE + rrl) = v4;
                }
            }
    } else {
        const float sc = (z == 0) ? 0.125f * 1.4426950408889634f : 1.0f;
#pragma unroll
        for (int tm = 0; tm < 2; ++tm)
#pragma unroll
            for (int tn = 0; tn < 2; ++tn) {
                int ddl = wn * 64 + tn * 32 + l31;
#pragma unroll
                for (int reg = 0; reg < 16; ++reg) {
                    int rrl = wm * 64 + tm * 32 + (reg & 3) + 8 * (reg >> 2) + 4 * lh;
                    Ct[rrl * TSTRIDE + ddl] = f2bf(acc[tm][tn][reg] * sc);
                }
            }
    }
    __syncthreads();

    const int bb = row0 >> 10;
#pragma unroll
    for (int it = 0; it < 8; ++it) {
        int row = it * 16 + (t >> 4);
        int ck = t & 15;
        bf16x8 v = *(const bf16x8*)(Ct + row * TSTRIDE + ck * 8);
        if (z == 2) {
            int gdd = col0 + row;
            int head = bb * 12 + (gdd >> 6);
            *(bf16x8*)(Vtg + ((size_t)head * 64 + (gdd & 63)) * 1024 + (row0 & 1023) + ck * 8) = v;
        } else {
            int rr = (row0 & 1023) + row;
            int gc = col0 + ck * 8;
            int head = bb * 12 + (gc >> 6);
            short* dst = (z == 0) ? Qg : Kg;
            *(bf16x8*)(dst + ((size_t)head * 1024 + rr) * 64 + (gc & 63)) = v;
        }
    }
}

// ---------------- LSE pass (base-2, S^T layout, 64-row A tiles) ----------------
// grid 1536: head = b%96 (keeps a head's blocks on one XCD), r0 = (b/96)*64
__global__ __launch_bounds__(256, 5) void lse_pass(
    const short* __restrict__ Aall, const short* __restrict__ Ball,
    const float* __restrict__ bias, float* __restrict__ outv,
    float bias_sign, float out_sign)
{
    __shared__ __align__(16) short At[64 * 64];
    __shared__ __align__(16) short Bt[128 * 64];
    __shared__ __align__(16) float biasl[1024];
    const int t = threadIdx.x;
    const int head = blockIdx.x % 96;
    const int r0 = (blockIdx.x / 96) * 64;
    const int lane = t & 63, w = t >> 6, quad = lane >> 4, c = lane & 15;
    const short* A = Aall + (size_t)head * 65536;
    const short* B = Ball + (size_t)head * 65536;

    stage_tile<2>(A + r0 * 64, 64, At, t);
    if (bias) {
        float4 v = ((const float4*)(bias + (size_t)head * 1024))[t];
        v.x *= bias_sign; v.y *= bias_sign; v.z *= bias_sign; v.w *= bias_sign;
        ((float4*)biasl)[t] = v;
    } else ((float4*)biasl)[t] = make_float4(0.f, 0.f, 0.f, 0.f);

    float lsum = 0.f;

    for (int j0 = 0; j0 < 1024; j0 += 128) {
        __syncthreads();
        stage_tile<4>(B + j0 * 64, 64, Bt, t);
        __syncthreads();
        f32x4 sacc[8];
#pragma unroll
        for (int fm = 0; fm < 8; ++fm) sacc[fm] = (f32x4){0.f, 0.f, 0.f, 0.f};
#pragma unroll
        for (int ks = 0; ks < 2; ++ks) {
            bf16x8 af[8], bfr;
#pragma unroll
            for (int fm = 0; fm < 8; ++fm) af[fm] = ldfrag(Bt, fm * 16 + c, ks * 4 + quad);
            bfr = ldfrag(At, w * 16 + c, ks * 4 + quad);
#pragma unroll
            for (int fm = 0; fm < 8; ++fm)
                sacc[fm] = __builtin_amdgcn_mfma_f32_16x16x32_bf16(af[fm], bfr, sacc[fm], 0, 0, 0);
        }
#pragma unroll
        for (int fm = 0; fm < 8; ++fm) {
            float4 b4 = *(const float4*)(biasl + j0 + fm * 16 + quad * 4);
            float p0 = __builtin_amdgcn_exp2f(sacc[fm][0] + b4.x);
            float p1 = __builtin_amdgcn_exp2f(sacc[fm][1] + b4.y);
            float p2 = __builtin_amdgcn_exp2f(sacc[fm][2] + b4.z);
            float p3 = __builtin_amdgcn_exp2f(sacc[fm][3] + b4.w);
            lsum += (p0 + p1) + (p2 + p3);
        }
    }

    lsum += __shfl_xor(lsum, 16);
    lsum += __shfl_xor(lsum, 32);
    if (quad == 0)
        outv[(size_t)head * 1024 + r0 + w * 16 + c] =
            out_sign * __builtin_amdgcn_logf(lsum);
}

// ---------------- flash pass (64-row Q tiles): ctx = (1/n) softmax2_j(S2+v1_2) @ V ----
// P never touches LDS (k-slot bijection; see R3 notes). Output is O^T.
__global__ __launch_bounds__(256, 5) void flash_pass(
    const short* __restrict__ Qall, const short* __restrict__ Kall,
    const short* __restrict__ Vtall, const float* __restrict__ v1,
    short* __restrict__ ctx)
{
    __shared__ __align__(16) short Qt[64 * 64];
    __shared__ __align__(16) short Kt[64 * 64];
    __shared__ __align__(16) short Vtl[64 * 64];
    __shared__ __align__(16) float v1l[1024];
    const int t = threadIdx.x;
    const int head = blockIdx.x % 96;
    const int r0 = (blockIdx.x / 96) * 64;
    const int lane = t & 63, w = t >> 6, quad = lane >> 4, c = lane & 15;
    const short* Q = Qall + (size_t)head * 65536;
    const short* K = Kall + (size_t)head * 65536;
    const short* Vt = Vtall + (size_t)head * 65536;

    stage_tile<2>(Q + r0 * 64, 64, Qt, t);
    ((float4*)v1l)[t] = ((const float4*)(v1 + (size_t)head * 1024))[t];

    float lsum = 0.f;
    f32x4 oacc[4];   // O^T tiles: m = d (4), single i-tile (wave's 16 rows)
#pragma unroll
    for (int md = 0; md < 4; ++md) oacc[md] = (f32x4){0.f, 0.f, 0.f, 0.f};

    for (int j0 = 0; j0 < 1024; j0 += 64) {
        __syncthreads();
        stage_tile<2>(K + j0 * 64, 64, Kt, t);
        stage_tile<2>(Vt + j0, 1024, Vtl, t);
        __syncthreads();
        f32x4 sacc[4];
#pragma unroll
        for (int fm = 0; fm < 4; ++fm) sacc[fm] = (f32x4){0.f, 0.f, 0.f, 0.f};
#pragma unroll
        for (int ks = 0; ks < 2; ++ks) {
            bf16x8 af[4], bfr;
#pragma unroll
            for (int fm = 0; fm < 4; ++fm) af[fm] = ldfrag(Kt, fm * 16 + c, ks * 4 + quad);
            bfr = ldfrag(Qt, w * 16 + c, ks * 4 + quad);
#pragma unroll
            for (int fm = 0; fm < 4; ++fm)
                sacc[fm] = __builtin_amdgcn_mfma_f32_16x16x32_bf16(af[fm], bfr, sacc[fm], 0, 0, 0);
        }
        unsigned pk[4][2];
#pragma unroll
        for (int fm = 0; fm < 4; ++fm) {
            float4 b4 = *(const float4*)(v1l + j0 + fm * 16 + quad * 4);
            float p0 = __builtin_amdgcn_exp2f(sacc[fm][0] + b4.x);
            float p1 = __builtin_amdgcn_exp2f(sacc[fm][1] + b4.y);
            float p2 = __builtin_amdgcn_exp2f(sacc[fm][2] + b4.z);
            float p3 = __builtin_amdgcn_exp2f(sacc[fm][3] + b4.w);
            lsum += (p0 + p1) + (p2 + p3);
            pk[fm][0] = pkbf(p0, p1);
            pk[fm][1] = pkbf(p2, p3);
        }
#pragma unroll
        for (int ks = 0; ks < 2; ++ks) {
            bf16x8 vaf[4];
#pragma unroll
            for (int md = 0; md < 4; ++md) {
                union { bf16x8 v8; bf16x4 h[2]; } u;
                u.h[0] = ldv4(Vtl, md * 16 + c, ks * 32 + quad * 4);
                u.h[1] = ldv4(Vtl, md * 16 + c, ks * 32 + 16 + quad * 4);
                vaf[md] = u.v8;
            }
            union { bf16x8 v8; unsigned u4[4]; } b;
            b.u4[0] = pk[2 * ks + 0][0];
            b.u4[1] = pk[2 * ks + 0][1];
            b.u4[2] = pk[2 * ks + 1][0];
            b.u4[3] = pk[2 * ks + 1][1];
#pragma unroll
            for (int md = 0; md < 4; ++md)
                oacc[md] = __builtin_amdgcn_mfma_f32_16x16x32_bf16(vaf[md], b.v8, oacc[md], 0, 0, 0);
        }
    }

    lsum += __shfl_xor(lsum, 16);
    lsum += __shfl_xor(lsum, 32);
    const int bb = head / 12, hh = head % 12;
    float nrm = __builtin_amdgcn_rcpf(1024.f * lsum);
    int rr = r0 + w * 16 + c;
#pragma unroll
    for (int md = 0; md < 4; ++md) {
        short4 v4;
        v4.x = f2bf(oacc[md][0] * nrm);
        v4.y = f2bf(oacc[md][1] * nrm);
        v4.z = f2bf(oacc[md][2] * nrm);
        v4.w = f2bf(oacc[md][3] * nrm);
        *(short4*)(ctx + ((size_t)(bb * 1024 + rr)) * 768 + hh * 64 + md * 16 + quad * 4) = v4;
    }
}

// ---------------- output projection (32x32x16 MFMA) ----------------
__global__ __launch_bounds__(256, 4) void out_gemm(
    const short* __restrict__ ctxb, const short* __restrict__ wo,
    const float* __restrict__ bo, float* __restrict__ out)
{
    __shared__ __align__(16) short At[128 * 64];
    __shared__ __align__(16) short Bt[128 * 64];
    const int t = threadIdx.x;
    const int row0 = blockIdx.x * 128, col0 = blockIdx.y * 128;
    const int lane = t & 63, w = t >> 6;
    const int l31 = lane & 31, lh = lane >> 5;
    const int wm = w >> 1, wn = w & 1;

    f32x16 acc[2][2];
#pragma unroll
    for (int i = 0; i < 2; ++i)
#pragma unroll
        for (int j = 0; j < 2; ++j) acc[i][j] = (f32x16)(0.f);

    for (int k0 = 0; k0 < 768; k0 += 64) {
        __syncthreads();
        stage_tile<4>(ctxb + (size_t)row0 * 768 + k0, 768, At, t);
        stage_tile<4>(wo + (size_t)col0 * 768 + k0, 768, Bt, t);
        __syncthreads();
#pragma unroll
        for (int s = 0; s < 4; ++s) {
            bf16x8 af[2], bfr[2];
#pragma unroll
            for (int tm = 0; tm < 2; ++tm) af[tm] = ldfrag(At, wm * 64 + tm * 32 + l31, s * 2 + lh);
#pragma unroll
            for (int tn = 0; tn < 2; ++tn) bfr[tn] = ldfrag(Bt, wn * 64 + tn * 32 + l31, s * 2 + lh);
#pragma unroll
            for (int tm = 0; tm < 2; ++tm)
#pragma unroll
                for (int tn = 0; tn < 2; ++tn)
                    acc[tm][tn] = __builtin_amdgcn_mfma_f32_32x32x16_bf16(af[tm], bfr[tn], acc[tm][tn], 0, 0, 0);
        }
    }
#pragma unroll
    for (int tm = 0; tm < 2; ++tm)
#pragma unroll
        for (int tn = 0; tn < 2; ++tn) {
            int gc = col0 + wn * 64 + tn * 32 + l31;
            float b = bo[gc];
#pragma unroll
            for (int reg = 0; reg < 16; ++reg) {
                int gr = row0 + wm * 64 + tm * 32 + (reg & 3) + 8 * (reg >> 2) + 4 * lh;
                out[(size_t)gr * 768 + gc] = acc[tm][tn][reg] + b;
            }
        }
}

extern "C" void kernel_launch(void* const* d_in, const int* in_sizes, int n_in,
                              void* d_out, int out_size, void* d_ws, size_t ws_size,
                              hipStream_t stream) {
    const float* x  = (const float*)d_in[0];
    const float* Wq = (const float*)d_in[1];
    const float* Wk = (const float*)d_in[2];
    const float* Wv = (const float*)d_in[3];
    const float* Wo = (const float*)d_in[4];
    const float* bo = (const float*)d_in[5];
    float* out = (float*)d_out;

    char* p = (char*)d_ws;
    short* xb  = (short*)p; p += (size_t)8192 * 768 * 2;
    short* wqb = (short*)p; p += (size_t)768 * 768 * 2;
    short* wkb = (short*)p; p += (size_t)768 * 768 * 2;
    short* wvb = (short*)p; p += (size_t)768 * 768 * 2;
    short* wob = (short*)p; p += (size_t)768 * 768 * 2;
    short* Qg  = (short*)p; p += (size_t)96 * 1024 * 64 * 2;
    short* Kg  = (short*)p; p += (size_t)96 * 1024 * 64 * 2;
    short* Vtg = (short*)p; p += (size_t)96 * 1024 * 64 * 2;
    float* r1  = (float*)p; p += (size_t)96 * 1024 * 4;
    float* v1  = (float*)p; p += (size_t)96 * 1024 * 4;
    short* ctx = (short*)p; p += (size_t)8192 * 768 * 2;

    cvt_all<<<6144 + 4 * 576, 256, 0, stream>>>(x, Wq, Wk, Wv, Wo, xb, wqb, wkb, wvb, wob);

    proj_gemm<<<dim3(64, 6, 3), 256, 0, stream>>>(xb, wqb, wkb, wvb, Qg, Kg, Vtg);

    // pass 1: r1_2[i] = +log2 sum_j exp2(S2[i,j])
    lse_pass<<<1536, 256, 0, stream>>>(Qg, Kg, nullptr, r1, 0.f, 1.f);
    // pass 2: v1_2[j] = -log2 sum_i exp2(S2[i,j] - r1_2[i])
    lse_pass<<<1536, 256, 0, stream>>>(Kg, Qg, r1, v1, -1.f, -1.f);

    flash_pass<<<1536, 256, 0, stream>>>(Qg, Kg, Vtg, v1, ctx);

    out_gemm<<<dim3(64, 6), 256, 0, stream>>>(ctx, wob, bo, out);
}

// Round 7
// 218.460 us; speedup vs baseline: 1.3776x; 1.0640x over previous
//
#include <hip/hip_runtime.h>

#define DEV __device__ __forceinline__

typedef __attribute__((ext_vector_type(4))) float f32x4;
typedef __attribute__((ext_vector_type(16))) float f32x16;
typedef __attribute__((ext_vector_type(8))) short bf16x8;
typedef __attribute__((ext_vector_type(4))) short bf16x4;

// round-to-nearest-even f32 -> bf16 (bits in a short)
DEV short f2bf(float f) {
    union { float f; unsigned u; } v; v.f = f;
    unsigned r = (v.u + 0x7fffu + ((v.u >> 16) & 1u)) >> 16;
    return (short)r;
}

#ifndef __has_builtin
#define __has_builtin(x) 0
#endif
#if __has_builtin(__builtin_amdgcn_cvt_pk_bf16_f32)
DEV unsigned pkbf(float a, float b) {
    auto r = __builtin_amdgcn_cvt_pk_bf16_f32(a, b);
    union { __typeof__(r) v; unsigned u; } u; u.v = r; return u.u;
}
#else
DEV unsigned pkbf(float a, float b) {
    return (unsigned)(unsigned short)f2bf(a) | ((unsigned)(unsigned short)f2bf(b) << 16);
}
#endif

// async global->LDS, 16 bytes per lane. LDS dest = wave-uniform base + lane*16.
DEV void gl_lds16(const void* g, void* l) {
    __builtin_amdgcn_global_load_lds(
        (__attribute__((address_space(1))) void*)(g),
        (__attribute__((address_space(3))) void*)(l), 16, 0, 0);
}

// Stage ITERS*32 rows x 64 bf16 cols from row-major global (stride ldg shorts)
// into LDS tile with row stride 64 shorts. 16B chunks XOR-swizzled.
template <int ITERS>
DEV void stage_tile(const short* g, int ldg, short* lds, int t) {
    const int w = t >> 6;
#pragma unroll
    for (int it = 0; it < ITERS; ++it) {
        int row = it * 32 + (t >> 3);
        int cx = (t & 7) ^ ((t >> 3) & 7);
        gl_lds16(g + row * ldg + cx * 8, (char*)lds + it * 4096 + (w << 10));
    }
}

// read 8-bf16 fragment: chunk kc (0..7) of tile row r (row stride 64 shorts)
DEV bf16x8 ldfrag(const short* lds, int r, int kc) {
    return *(const bf16x8*)(lds + r * 64 + ((kc ^ (r & 7)) << 3));
}

// ---------------- conversion (all 5 tensors in one launch) ----------------
__global__ void cvt_all(const float* __restrict__ x,
                        const float* __restrict__ wq, const float* __restrict__ wk,
                        const float* __restrict__ wv, const float* __restrict__ wo,
                        short* __restrict__ xb,
                        short* __restrict__ wqb, short* __restrict__ wkb,
                        short* __restrict__ wvb, short* __restrict__ wob) {
    int b = blockIdx.x;
    const float* s; short* d; int i;
    if (b < 6144) {
        s = x; d = xb; i = b * 256 + threadIdx.x;
    } else {
        int r = b - 6144;
        int wi = r / 576, rem = r - wi * 576;
        s = (wi == 0) ? wq : (wi == 1) ? wk : (wi == 2) ? wv : wo;
        d = (wi == 0) ? wqb : (wi == 1) ? wkb : (wi == 2) ? wvb : wob;
        i = rem * 256 + threadIdx.x;
    }
    float4 v = ((const float4*)s)[i];
    short4 o;
    o.x = f2bf(v.x); o.y = f2bf(v.y); o.z = f2bf(v.z); o.w = f2bf(v.w);
    ((short4*)d)[i] = o;
}

// ---------------- QKV projection GEMM (32x32x16 MFMA) ----------------
// Q gets scale (1/8)*log2(e) folded (base-2 domain downstream).
// V^T is stored with token columns PERMUTED within each 64-token group:
// n = (j&32) | ((j&12)<<1) | ((j&16)>>2) | (j&3), so flash's PV A-fragment
// is a single conflict-free ldfrag (matches the in-register P B-frag k-map).
#define TSTRIDE 136
__global__ __launch_bounds__(256, 4) void proj_gemm(
    const short* __restrict__ xb,
    const short* __restrict__ wq, const short* __restrict__ wk, const short* __restrict__ wv,
    short* __restrict__ Qg, short* __restrict__ Kg, short* __restrict__ Vtg)
{
    __shared__ __align__(16) char smem[128 * TSTRIDE * 2];
    short* At = (short*)smem;
    short* Bt = (short*)(smem + 128 * 64 * 2);
    short* Ct = (short*)smem;
    const int t = threadIdx.x;
    const int z = blockIdx.z;
    const int row0 = blockIdx.x * 128, col0 = blockIdx.y * 128;
    const int lane = t & 63, w = t >> 6;
    const int l31 = lane & 31, lh = lane >> 5;
    const int wm = w >> 1, wn = w & 1;
    const short* W = (z == 0) ? wq : (z == 1) ? wk : wv;

    f32x16 acc[2][2];
#pragma unroll
    for (int i = 0; i < 2; ++i)
#pragma unroll
        for (int j = 0; j < 2; ++j) acc[i][j] = (f32x16)(0.f);

    for (int k0 = 0; k0 < 768; k0 += 64) {
        __syncthreads();
        stage_tile<4>(xb + (size_t)row0 * 768 + k0, 768, At, t);
        stage_tile<4>(W + (size_t)col0 * 768 + k0, 768, Bt, t);
        __syncthreads();
#pragma unroll
        for (int s = 0; s < 4; ++s) {
            bf16x8 af[2], bfr[2];
#pragma unroll
            for (int tm = 0; tm < 2; ++tm) af[tm] = ldfrag(At, wm * 64 + tm * 32 + l31, s * 2 + lh);
#pragma unroll
            for (int tn = 0; tn < 2; ++tn) bfr[tn] = ldfrag(Bt, wn * 64 + tn * 32 + l31, s * 2 + lh);
#pragma unroll
            for (int tm = 0; tm < 2; ++tm)
#pragma unroll
                for (int tn = 0; tn < 2; ++tn)
                    acc[tm][tn] = __builtin_amdgcn_mfma_f32_32x32x16_bf16(af[tm], bfr[tn], acc[tm][tn], 0, 0, 0);
        }
    }

    __syncthreads();
    if (z == 2) {
#pragma unroll
        for (int tm = 0; tm < 2; ++tm)
#pragma unroll
            for (int tn = 0; tn < 2; ++tn) {
                int ddl = wn * 64 + tn * 32 + l31;
#pragma unroll
                for (int g = 0; g < 4; ++g) {
                    int rrl = wm * 64 + tm * 32 + 8 * g + 4 * lh;   // token base, %4==0
                    int j6 = rrl & 63;
                    int pp = (rrl & ~63) | (j6 & 32) | ((j6 & 12) << 1) | ((j6 & 16) >> 2);
                    short4 v4;
                    v4.x = f2bf(acc[tm][tn][4 * g + 0]);
                    v4.y = f2bf(acc[tm][tn][4 * g + 1]);
                    v4.z = f2bf(acc[tm][tn][4 * g + 2]);
                    v4.w = f2bf(acc[tm][tn][4 * g + 3]);
                    *(short4*)(Ct + ddl * TSTRIDE + pp) = v4;
                }
            }
    } else {
        const float sc = (z == 0) ? 0.125f * 1.4426950408889634f : 1.0f;
#pragma unroll
        for (int tm = 0; tm < 2; ++tm)
#pragma unroll
            for (int tn = 0; tn < 2; ++tn) {
                int ddl = wn * 64 + tn * 32 + l31;
#pragma unroll
                for (int reg = 0; reg < 16; ++reg) {
                    int rrl = wm * 64 + tm * 32 + (reg & 3) + 8 * (reg >> 2) + 4 * lh;
                    Ct[rrl * TSTRIDE + ddl] = f2bf(acc[tm][tn][reg] * sc);
                }
            }
    }
    __syncthreads();

    const int bb = row0 >> 10;
#pragma unroll
    for (int it = 0; it < 8; ++it) {
        int row = it * 16 + (t >> 4);
        int ck = t & 15;
        bf16x8 v = *(const bf16x8*)(Ct + row * TSTRIDE + ck * 8);
        if (z == 2) {
            int gdd = col0 + row;
            int head = bb * 12 + (gdd >> 6);
            *(bf16x8*)(Vtg + ((size_t)head * 64 + (gdd & 63)) * 1024 + (row0 & 1023) + ck * 8) = v;
        } else {
            int rr = (row0 & 1023) + row;
            int gc = col0 + ck * 8;
            int head = bb * 12 + (gc >> 6);
            short* dst = (z == 0) ? Qg : Kg;
            *(bf16x8*)(dst + ((size_t)head * 1024 + rr) * 64 + (gc & 63)) = v;
        }
    }
}

// ---------------- LSE pass (base-2, S^T layout, 64-row A tiles) ----------------
// bias folded into MFMA C-init. grid 1536: head = b%96, r0 = (b/96)*64
__global__ __launch_bounds__(256, 5) void lse_pass(
    const short* __restrict__ Aall, const short* __restrict__ Ball,
    const float* __restrict__ bias, float* __restrict__ outv,
    float bias_sign, float out_sign)
{
    __shared__ __align__(16) short At[64 * 64];
    __shared__ __align__(16) short Bt[128 * 64];
    __shared__ __align__(16) float biasl[1024];
    const int t = threadIdx.x;
    const int head = blockIdx.x % 96;
    const int r0 = (blockIdx.x / 96) * 64;
    const int lane = t & 63, w = t >> 6, quad = lane >> 4, c = lane & 15;
    const short* A = Aall + (size_t)head * 65536;
    const short* B = Ball + (size_t)head * 65536;

    stage_tile<2>(A + r0 * 64, 64, At, t);
    if (bias) {
        float4 v = ((const float4*)(bias + (size_t)head * 1024))[t];
        v.x *= bias_sign; v.y *= bias_sign; v.z *= bias_sign; v.w *= bias_sign;
        ((float4*)biasl)[t] = v;
    } else ((float4*)biasl)[t] = make_float4(0.f, 0.f, 0.f, 0.f);

    float lsum = 0.f;

    for (int j0 = 0; j0 < 1024; j0 += 128) {
        __syncthreads();
        stage_tile<4>(B + j0 * 64, 64, Bt, t);
        __syncthreads();
        f32x4 sacc[8];
#pragma unroll
        for (int fm = 0; fm < 8; ++fm) {
            float4 b4 = *(const float4*)(biasl + j0 + fm * 16 + quad * 4);
            sacc[fm] = (f32x4){b4.x, b4.y, b4.z, b4.w};
        }
#pragma unroll
        for (int ks = 0; ks < 2; ++ks) {
            bf16x8 af[8], bfr;
#pragma unroll
            for (int fm = 0; fm < 8; ++fm) af[fm] = ldfrag(Bt, fm * 16 + c, ks * 4 + quad);
            bfr = ldfrag(At, w * 16 + c, ks * 4 + quad);
#pragma unroll
            for (int fm = 0; fm < 8; ++fm)
                sacc[fm] = __builtin_amdgcn_mfma_f32_16x16x32_bf16(af[fm], bfr, sacc[fm], 0, 0, 0);
        }
#pragma unroll
        for (int fm = 0; fm < 8; ++fm) {
            float p0 = __builtin_amdgcn_exp2f(sacc[fm][0]);
            float p1 = __builtin_amdgcn_exp2f(sacc[fm][1]);
            float p2 = __builtin_amdgcn_exp2f(sacc[fm][2]);
            float p3 = __builtin_amdgcn_exp2f(sacc[fm][3]);
            lsum += (p0 + p1) + (p2 + p3);
        }
    }

    lsum += __shfl_xor(lsum, 16);
    lsum += __shfl_xor(lsum, 32);
    if (quad == 0)
        outv[(size_t)head * 1024 + r0 + w * 16 + c] =
            out_sign * __builtin_amdgcn_logf(lsum);
}

// ---------------- flash pass (128-row Q tiles, grid 768) ----------------
// P never touches LDS (k-slot bijection); V^T arrives pre-permuted so the
// PV A-frag is a single ldfrag. v1 bias folded into S MFMA C-init. Output O^T.
__global__ __launch_bounds__(256, 4) void flash_pass(
    const short* __restrict__ Qall, const short* __restrict__ Kall,
    const short* __restrict__ Vtall, const float* __restrict__ v1,
    short* __restrict__ ctx)
{
    __shared__ __align__(16) short Qt[128 * 64];
    __shared__ __align__(16) short Kt[64 * 64];
    __shared__ __align__(16) short Vtl[64 * 64];
    __shared__ __align__(16) float v1l[1024];
    const int t = threadIdx.x;
    const int head = blockIdx.x % 96;
    const int r0 = (blockIdx.x / 96) * 128;
    const int lane = t & 63, w = t >> 6, quad = lane >> 4, c = lane & 15;
    const short* Q = Qall + (size_t)head * 65536;
    const short* K = Kall + (size_t)head * 65536;
    const short* Vt = Vtall + (size_t)head * 65536;

    stage_tile<4>(Q + r0 * 64, 64, Qt, t);
    ((float4*)v1l)[t] = ((const float4*)(v1 + (size_t)head * 1024))[t];

    float lsum[2] = {0.f, 0.f};
    f32x4 oacc[4][2];   // O^T tiles: m = d (4), n = i (2)
#pragma unroll
    for (int md = 0; md < 4; ++md)
#pragma unroll
        for (int ni = 0; ni < 2; ++ni) oacc[md][ni] = (f32x4){0.f, 0.f, 0.f, 0.f};

    for (int j0 = 0; j0 < 1024; j0 += 64) {
        __syncthreads();
        stage_tile<2>(K + j0 * 64, 64, Kt, t);
        stage_tile<2>(Vt + j0, 1024, Vtl, t);
        __syncthreads();
        // S^T strip with v1 bias pre-loaded into the accumulator
        f32x4 sacc[4][2];
#pragma unroll
        for (int fm = 0; fm < 4; ++fm) {
            float4 b4 = *(const float4*)(v1l + j0 + fm * 16 + quad * 4);
#pragma unroll
            for (int fn = 0; fn < 2; ++fn) sacc[fm][fn] = (f32x4){b4.x, b4.y, b4.z, b4.w};
        }
#pragma unroll
        for (int ks = 0; ks < 2; ++ks) {
            bf16x8 af[4], bfr[2];
#pragma unroll
            for (int fm = 0; fm < 4; ++fm) af[fm] = ldfrag(Kt, fm * 16 + c, ks * 4 + quad);
#pragma unroll
            for (int fn = 0; fn < 2; ++fn) bfr[fn] = ldfrag(Qt, w * 32 + fn * 16 + c, ks * 4 + quad);
#pragma unroll
            for (int fm = 0; fm < 4; ++fm)
#pragma unroll
                for (int fn = 0; fn < 2; ++fn)
                    sacc[fm][fn] = __builtin_amdgcn_mfma_f32_16x16x32_bf16(af[fm], bfr[fn], sacc[fm][fn], 0, 0, 0);
        }
        unsigned pk[4][2][2];
#pragma unroll
        for (int fm = 0; fm < 4; ++fm)
#pragma unroll
            for (int fn = 0; fn < 2; ++fn) {
                float p0 = __builtin_amdgcn_exp2f(sacc[fm][fn][0]);
                float p1 = __builtin_amdgcn_exp2f(sacc[fm][fn][1]);
                float p2 = __builtin_amdgcn_exp2f(sacc[fm][fn][2]);
                float p3 = __builtin_amdgcn_exp2f(sacc[fm][fn][3]);
                lsum[fn] += (p0 + p1) + (p2 + p3);
                pk[fm][fn][0] = pkbf(p0, p1);
                pk[fm][fn][1] = pkbf(p2, p3);
            }
#pragma unroll
        for (int ks = 0; ks < 2; ++ks) {
            bf16x8 vaf[4];
#pragma unroll
            for (int md = 0; md < 4; ++md) vaf[md] = ldfrag(Vtl, md * 16 + c, ks * 4 + quad);
#pragma unroll
            for (int ni = 0; ni < 2; ++ni) {
                union { bf16x8 v8; unsigned u4[4]; } b;
                b.u4[0] = pk[2 * ks + 0][ni][0];
                b.u4[1] = pk[2 * ks + 0][ni][1];
                b.u4[2] = pk[2 * ks + 1][ni][0];
                b.u4[3] = pk[2 * ks + 1][ni][1];
#pragma unroll
                for (int md = 0; md < 4; ++md)
                    oacc[md][ni] = __builtin_amdgcn_mfma_f32_16x16x32_bf16(vaf[md], b.v8, oacc[md][ni], 0, 0, 0);
            }
        }
    }

#pragma unroll
    for (int fn = 0; fn < 2; ++fn) {
        float s = lsum[fn];
        s += __shfl_xor(s, 16); s += __shfl_xor(s, 32);
        lsum[fn] = s;
    }
    const int bb = head / 12, hh = head % 12;
#pragma unroll
    for (int ni = 0; ni < 2; ++ni) {
        float nrm = __builtin_amdgcn_rcpf(1024.f * lsum[ni]);
        int rr = r0 + w * 32 + ni * 16 + c;
#pragma unroll
        for (int md = 0; md < 4; ++md) {
            short4 v4;
            v4.x = f2bf(oacc[md][ni][0] * nrm);
            v4.y = f2bf(oacc[md][ni][1] * nrm);
            v4.z = f2bf(oacc[md][ni][2] * nrm);
            v4.w = f2bf(oacc[md][ni][3] * nrm);
            *(short4*)(ctx + ((size_t)(bb * 1024 + rr)) * 768 + hh * 64 + md * 16 + quad * 4) = v4;
        }
    }
}

// ---------------- output projection (32x32x16 MFMA) ----------------
__global__ __launch_bounds__(256, 4) void out_gemm(
    const short* __restrict__ ctxb, const short* __restrict__ wo,
    const float* __restrict__ bo, float* __restrict__ out)
{
    __shared__ __align__(16) short At[128 * 64];
    __shared__ __align__(16) short Bt[128 * 64];
    const int t = threadIdx.x;
    const int row0 = blockIdx.x * 128, col0 = blockIdx.y * 128;
    const int lane = t & 63, w = t >> 6;
    const int l31 = lane & 31, lh = lane >> 5;
    const int wm = w >> 1, wn = w & 1;

    f32x16 acc[2][2];
#pragma unroll
    for (int i = 0; i < 2; ++i)
#pragma unroll
        for (int j = 0; j < 2; ++j) acc[i][j] = (f32x16)(0.f);

    for (int k0 = 0; k0 < 768; k0 += 64) {
        __syncthreads();
        stage_tile<4>(ctxb + (size_t)row0 * 768 + k0, 768, At, t);
        stage_tile<4>(wo + (size_t)col0 * 768 + k0, 768, Bt, t);
        __syncthreads();
#pragma unroll
        for (int s = 0; s < 4; ++s) {
            bf16x8 af[2], bfr[2];
#pragma unroll
            for (int tm = 0; tm < 2; ++tm) af[tm] = ldfrag(At, wm * 64 + tm * 32 + l31, s * 2 + lh);
#pragma unroll
            for (int tn = 0; tn < 2; ++tn) bfr[tn] = ldfrag(Bt, wn * 64 + tn * 32 + l31, s * 2 + lh);
#pragma unroll
            for (int tm = 0; tm < 2; ++tm)
#pragma unroll
                for (int tn = 0; tn < 2; ++tn)
                    acc[tm][tn] = __builtin_amdgcn_mfma_f32_32x32x16_bf16(af[tm], bfr[tn], acc[tm][tn], 0, 0, 0);
        }
    }
#pragma unroll
    for (int tm = 0; tm < 2; ++tm)
#pragma unroll
        for (int tn = 0; tn < 2; ++tn) {
            int gc = col0 + wn * 64 + tn * 32 + l31;
            float b = bo[gc];
#pragma unroll
            for (int reg = 0; reg < 16; ++reg) {
                int gr = row0 + wm * 64 + tm * 32 + (reg & 3) + 8 * (reg >> 2) + 4 * lh;
                out[(size_t)gr * 768 + gc] = acc[tm][tn][reg] + b;
            }
        }
}

extern "C" void kernel_launch(void* const* d_in, const int* in_sizes, int n_in,
                              void* d_out, int out_size, void* d_ws, size_t ws_size,
                              hipStream_t stream) {
    const float* x  = (const float*)d_in[0];
    const float* Wq = (const float*)d_in[1];
    const float* Wk = (const float*)d_in[2];
    const float* Wv = (const float*)d_in[3];
    const float* Wo = (const float*)d_in[4];
    const float* bo = (const float*)d_in[5];
    float* out = (float*)d_out;

    char* p = (char*)d_ws;
    short* xb  = (short*)p; p += (size_t)8192 * 768 * 2;
    short* wqb = (short*)p; p += (size_t)768 * 768 * 2;
    short* wkb = (short*)p; p += (size_t)768 * 768 * 2;
    short* wvb = (short*)p; p += (size_t)768 * 768 * 2;
    short* wob = (short*)p; p += (size_t)768 * 768 * 2;
    short* Qg  = (short*)p; p += (size_t)96 * 1024 * 64 * 2;
    short* Kg  = (short*)p; p += (size_t)96 * 1024 * 64 * 2;
    short* Vtg = (short*)p; p += (size_t)96 * 1024 * 64 * 2;
    float* r1  = (float*)p; p += (size_t)96 * 1024 * 4;
    float* v1  = (float*)p; p += (size_t)96 * 1024 * 4;
    short* ctx = (short*)p; p += (size_t)8192 * 768 * 2;

    cvt_all<<<6144 + 4 * 576, 256, 0, stream>>>(x, Wq, Wk, Wv, Wo, xb, wqb, wkb, wvb, wob);

    proj_gemm<<<dim3(64, 6, 3), 256, 0, stream>>>(xb, wqb, wkb, wvb, Qg, Kg, Vtg);

    // pass 1: r1_2[i] = +log2 sum_j exp2(S2[i,j])
    lse_pass<<<1536, 256, 0, stream>>>(Qg, Kg, nullptr, r1, 0.f, 1.f);
    // pass 2: v1_2[j] = -log2 sum_i exp2(S2[i,j] - r1_2[i])
    lse_pass<<<1536, 256, 0, stream>>>(Kg, Qg, r1, v1, -1.f, -1.f);

    flash_pass<<<768, 256, 0, stream>>>(Qg, Kg, Vtg, v1, ctx);

    out_gemm<<<dim3(64, 6), 256, 0, stream>>>(ctx, wob, bo, out);
}